// Round 2
// baseline (872.287 us; speedup 1.0000x reference)
//
#include <hip/hip_runtime.h>

// ---------- common helpers ----------
typedef __bf16 bf16x8 __attribute__((ext_vector_type(8)));
typedef float f32x4 __attribute__((ext_vector_type(4)));

__device__ __forceinline__ ushort f2b(float f) {
    union { float f; unsigned int i; } v;
    v.f = f;
    unsigned int x = v.i;
    unsigned int r = (x + 0x7fffu + ((x >> 16) & 1u)) >> 16;
    return (ushort)r;
}

#define D_MODEL 1024
#define D_INNER 2048
#define D_STATE 16
#define DT_RANK 64
#define NTOK    2048   // B*L
#define LSEQ    1024

// ---------- K0: f32 -> bf16 weight conversion ----------
__global__ __launch_bounds__(256) void cvt_bf16_kernel(
    const float* __restrict__ src, ushort* __restrict__ dst, int n4)
{
    int i = blockIdx.x * 256 + threadIdx.x;
    if (i >= n4) return;
    float4 v = *(const float4*)(src + i * 4);
    ushort4 o;
    o.x = f2b(v.x); o.y = f2b(v.y); o.z = f2b(v.z); o.w = f2b(v.w);
    *(ushort4*)(dst + i * 4) = o;
}

// ---------- K1: RMSNorm (f32 in, bf16 h out) + residual f32 copy ----------
__global__ __launch_bounds__(256) void rmsnorm_kernel(
    const float* __restrict__ hs, const float* __restrict__ w,
    ushort* __restrict__ hout, float* __restrict__ resid)
{
    int t = blockIdx.x;
    int tid = threadIdx.x;
    float4 r4 = *(const float4*)(hs + (size_t)t * D_MODEL + tid * 4);
    float s = r4.x * r4.x + r4.y * r4.y + r4.z * r4.z + r4.w * r4.w;
    #pragma unroll
    for (int off = 32; off >= 1; off >>= 1) s += __shfl_xor(s, off);
    __shared__ float red[4];
    int lane = tid & 63, wid = tid >> 6;
    if (lane == 0) red[wid] = s;
    __syncthreads();
    float tot = red[0] + red[1] + red[2] + red[3];
    float inv = 1.0f / (sqrtf(tot) * (1.0f / 32.0f) + 1e-5f);
    float4 w4 = *(const float4*)(w + tid * 4);
    ushort4 o;
    o.x = f2b(w4.x * r4.x * inv);
    o.y = f2b(w4.y * r4.y * inv);
    o.z = f2b(w4.z * r4.z * inv);
    o.w = f2b(w4.w * r4.w * inv);
    *(ushort4*)(hout + (size_t)t * D_MODEL + tid * 4) = o;
    *(float4*)(resid + (size_t)t * D_MODEL + tid * 4) = r4;   // exact copy
}

// ---------- MFMA GEMM: C(MxN) = A(MxK) @ W(NxK)^T, bf16 in, f32 out ----------
__global__ __launch_bounds__(256) void gemm_bt_kernel(
    const ushort* __restrict__ Ag, const ushort* __restrict__ Wg,
    float* __restrict__ Cf, int M, int N, int K)
{
    __shared__ __align__(16) ushort sA[128 * 32];
    __shared__ __align__(16) ushort sB[128 * 32];
    int tid = threadIdx.x;
    int bm = blockIdx.x, bn = blockIdx.y;
    int wid = tid >> 6, lane = tid & 63;
    int wm = (wid >> 1) * 64, wn = (wid & 1) * 64;
    int l16 = lane & 15, q = lane >> 4;

    f32x4 acc[4][4];
    #pragma unroll
    for (int i = 0; i < 4; i++)
        #pragma unroll
        for (int j = 0; j < 4; j++)
            acc[i][j] = (f32x4){0.f, 0.f, 0.f, 0.f};

    const ushort* Abase = Ag + (size_t)bm * 128 * K;
    const ushort* Wbase = Wg + (size_t)bn * 128 * K;

    for (int k0 = 0; k0 < K; k0 += 32) {
        __syncthreads();
        #pragma unroll
        for (int i = tid; i < 512; i += 256) {
            int r = i >> 2, c = (i & 3) << 3;
            *(uint4*)(sA + i * 8) = *(const uint4*)(Abase + (size_t)r * K + k0 + c);
            *(uint4*)(sB + i * 8) = *(const uint4*)(Wbase + (size_t)r * K + k0 + c);
        }
        __syncthreads();
        bf16x8 af[4], bfr[4];
        #pragma unroll
        for (int i = 0; i < 4; i++)
            af[i] = *(const bf16x8*)(sA + (wm + i * 16 + l16) * 32 + q * 8);
        #pragma unroll
        for (int j = 0; j < 4; j++)
            bfr[j] = *(const bf16x8*)(sB + (wn + j * 16 + l16) * 32 + q * 8);
        #pragma unroll
        for (int i = 0; i < 4; i++)
            #pragma unroll
            for (int j = 0; j < 4; j++)
                acc[i][j] = __builtin_amdgcn_mfma_f32_16x16x32_bf16(af[i], bfr[j], acc[i][j], 0, 0, 0);
    }

    int row0 = bm * 128 + wm + q * 4;
    int col0 = bn * 128 + wn + l16;
    #pragma unroll
    for (int i = 0; i < 4; i++)
        #pragma unroll
        for (int j = 0; j < 4; j++)
            #pragma unroll
            for (int r = 0; r < 4; r++)
                Cf[(size_t)(row0 + i * 16 + r) * N + col0 + j * 16] = acc[i][j][r];
}

// ---------- K3: causal depthwise conv (4 taps) + SiLU ----------
__global__ __launch_bounds__(256) void conv_silu_kernel(
    const float* __restrict__ xz, const float* __restrict__ cw,
    const float* __restrict__ cb, float* __restrict__ xc)
{
    int idx = blockIdx.x * 256 + threadIdx.x;     // (token, d) flat over 4M
    int d = idx & (D_INNER - 1);
    int t = idx >> 11;
    int l = t & (LSEQ - 1), b = t >> 10;
    float4 w4 = *(const float4*)(cw + d * 4);
    float acc = cb[d];
    float wk[4] = {w4.x, w4.y, w4.z, w4.w};
    #pragma unroll
    for (int k = 0; k < 4; k++) {
        int ll = l - 3 + k;
        float xv = (ll >= 0) ? xz[(((size_t)(b * LSEQ + ll)) << 12) + d] : 0.f;
        acc += xv * wk[k];
    }
    xc[idx] = acc / (1.f + __expf(-acc));
}

// ---------- K4: per-token x_proj (96 outs) + dt_proj + softplus ----------
__global__ __launch_bounds__(256) void xdbl_dt_kernel(
    const float* __restrict__ xc, const float* __restrict__ xprojw,
    const float* __restrict__ dtw, const float* __restrict__ dtb,
    float* __restrict__ xdbl, float* __restrict__ dtout)
{
    int t = blockIdx.x;
    int tid = threadIdx.x, lane = tid & 63, wid = tid >> 6;
    __shared__ float dtin[DT_RANK];

    // each lane caches its 32-element chunk of the xc row
    const float* xcrow = xc + (size_t)t * D_INNER + lane * 32;
    float xck[32];
    #pragma unroll
    for (int i = 0; i < 32; i++) xck[i] = xcrow[i];

    // wave w computes outputs n = w*24 .. w*24+23
    for (int nn = 0; nn < 24; nn++) {
        int n = wid * 24 + nn;
        const float* wr = xprojw + (size_t)n * D_INNER + lane * 32;
        float s = 0.f;
        #pragma unroll
        for (int i = 0; i < 32; i++) s += xck[i] * wr[i];
        #pragma unroll
        for (int off = 32; off >= 1; off >>= 1) s += __shfl_xor(s, off);
        if (lane == 0) {
            xdbl[(size_t)t * 96 + n] = s;
            if (n < DT_RANK) dtin[n] = s;
        }
    }
    __syncthreads();

    // dt = softplus(dtin @ dtw^T + dtb), each thread does 8 channels
    #pragma unroll
    for (int j = 0; j < 8; j++) {
        int d = tid + j * 256;
        const float* w = dtw + (size_t)d * DT_RANK;
        float s = dtb[d];
        #pragma unroll
        for (int r = 0; r < DT_RANK; r++) s += dtin[r] * w[r];
        dtout[(size_t)t * D_INNER + d] = (s > 20.f) ? s : log1pf(__expf(s));
    }
}

// ---------- K5: selective scan + D-skip + SiLU(z) gating -> bf16 yg ----------
__global__ __launch_bounds__(256) void scan_kernel(
    const float* __restrict__ dt, const float* __restrict__ xc,
    const float* __restrict__ xdbl, const float* __restrict__ xz,
    const float* __restrict__ Alog, const float* __restrict__ Dp,
    ushort* __restrict__ yg)
{
    int bid = blockIdx.x;          // 256 blocks
    int b = bid >> 7;
    int dbase = (bid & 127) * 16;
    int tid = threadIdx.x;
    int n = tid & 15;
    int d = dbase + (tid >> 4);

    float A = -__expf(Alog[d * D_STATE + n]);
    float Dd = Dp[d];
    float h = 0.f;

    const float* dtp = dt + (size_t)b * LSEQ * D_INNER + d;
    const float* xcp = xc + (size_t)b * LSEQ * D_INNER + d;
    const float* zp  = xz + (size_t)b * LSEQ * (2 * D_INNER) + D_INNER + d;
    const float* Bp  = xdbl + (size_t)b * LSEQ * 96 + 64 + n;
    const float* Cp  = Bp + 16;
    ushort* yp = yg + (size_t)b * LSEQ * D_INNER + d;

    float dtv = dtp[0], xcv = xcp[0], Bv = Bp[0], Cv = Cp[0], zv = zp[0];
    for (int l = 0; l < LSEQ; l++) {
        float ndt = 0.f, nxc = 0.f, nB = 0.f, nC = 0.f, nz = 0.f;
        if (l < LSEQ - 1) {   // prefetch next step
            ndt = dtp[(size_t)(l + 1) * D_INNER];
            nxc = xcp[(size_t)(l + 1) * D_INNER];
            nB  = Bp[(size_t)(l + 1) * 96];
            nC  = Cp[(size_t)(l + 1) * 96];
            nz  = zp[(size_t)(l + 1) * (2 * D_INNER)];
        }
        float dA = __expf(dtv * A);
        h = dA * h + dtv * xcv * Bv;
        float p = h * Cv;
        p += __shfl_xor(p, 1);
        p += __shfl_xor(p, 2);
        p += __shfl_xor(p, 4);
        p += __shfl_xor(p, 8);
        if (n == 0) {
            float y = p + Dd * xcv;
            float sz = zv / (1.f + __expf(-zv));
            yp[(size_t)l * D_INNER] = f2b(y * sz);
        }
        dtv = ndt; xcv = nxc; Bv = nB; Cv = nC; zv = nz;
    }
}

// ---------- K6 epilogue variant: GEMM writing f32 is reused (gemm_bt_kernel) ----------

extern "C" void kernel_launch(void* const* d_in, const int* in_sizes, int n_in,
                              void* d_out, int out_size, void* d_ws, size_t ws_size,
                              hipStream_t stream)
{
    const float* hs      = (const float*)d_in[0];
    const float* norm_w  = (const float*)d_in[1];
    const float* inproj  = (const float*)d_in[2];
    const float* convw   = (const float*)d_in[3];
    const float* convb   = (const float*)d_in[4];
    const float* xprojw  = (const float*)d_in[5];
    const float* dtw     = (const float*)d_in[6];
    const float* dtb     = (const float*)d_in[7];
    const float* alog    = (const float*)d_in[8];
    const float* dvec    = (const float*)d_in[9];
    const float* outproj = (const float*)d_in[10];

    float* out_main  = (float*)d_out;                        // (B,L,D_MODEL) f32
    float* out_resid = (float*)d_out + (size_t)NTOK * D_MODEL;

    char* ws = (char*)d_ws;
    float*  xz_f32  = (float*)(ws);                          // 2048*4096 f32  (32MB)
    float*  xc_f32  = (float*)(ws + 33554432);               // 2048*2048 f32  (16MB)
    float*  dt_f32  = (float*)(ws + 50331648);               // 2048*2048 f32  (16MB)
    float*  xdbl    = (float*)(ws + 67108864);               // 2048*96 f32    (768KB)
    ushort* h_bf16  = (ushort*)(ws + 67895296);              // 2048*1024 bf16 (4MB)
    ushort* yg_bf16 = (ushort*)(ws + 72089600);              // 2048*2048 bf16 (8MB)
    ushort* wIn     = (ushort*)(ws + 80478208);              // 4096*1024 bf16 (8MB)
    ushort* wOut    = (ushort*)(ws + 88866816);              // 1024*2048 bf16 (4MB)

    // K0: convert GEMM weights to bf16
    cvt_bf16_kernel<<<(2 * D_INNER * D_MODEL / 4 + 255) / 256, 256, 0, stream>>>(
        inproj, wIn, 2 * D_INNER * D_MODEL / 4);
    cvt_bf16_kernel<<<(D_MODEL * D_INNER / 4 + 255) / 256, 256, 0, stream>>>(
        outproj, wOut, D_MODEL * D_INNER / 4);

    // K1: RMSNorm + residual copy
    rmsnorm_kernel<<<NTOK, 256, 0, stream>>>(hs, norm_w, h_bf16, out_resid);

    // K2: xz = h @ in_proj_w^T  (2048 x 4096 x 1024) -> f32
    gemm_bt_kernel<<<dim3(NTOK / 128, (2 * D_INNER) / 128), 256, 0, stream>>>(
        h_bf16, wIn, xz_f32, NTOK, 2 * D_INNER, D_MODEL);

    // K3: conv + SiLU
    conv_silu_kernel<<<(NTOK * D_INNER) / 256, 256, 0, stream>>>(
        xz_f32, convw, convb, xc_f32);

    // K4: x_dbl + dt
    xdbl_dt_kernel<<<NTOK, 256, 0, stream>>>(xc_f32, xprojw, dtw, dtb, xdbl, dt_f32);

    // K5: selective scan + gating -> bf16
    scan_kernel<<<256, 256, 0, stream>>>(dt_f32, xc_f32, xdbl, xz_f32, alog, dvec, yg_bf16);

    // K6: out = yg @ out_proj_w^T  (2048 x 1024 x 2048) -> f32 into d_out
    gemm_bt_kernel<<<dim3(NTOK / 128, D_MODEL / 128), 256, 0, stream>>>(
        yg_bf16, wOut, out_main, NTOK, D_MODEL, D_INNER);
}

// Round 3
// 644.727 us; speedup vs baseline: 1.3530x; 1.3530x over previous
//
#include <hip/hip_runtime.h>

// ---------- common helpers ----------
typedef __bf16 bf16x8 __attribute__((ext_vector_type(8)));
typedef float f32x4 __attribute__((ext_vector_type(4)));

__device__ __forceinline__ ushort f2b(float f) {
    union { float f; unsigned int i; } v;
    v.f = f;
    unsigned int x = v.i;
    unsigned int r = (x + 0x7fffu + ((x >> 16) & 1u)) >> 16;
    return (ushort)r;
}

#define D_MODEL 1024
#define D_INNER 2048
#define D_STATE 16
#define DT_RANK 64
#define NTOK    2048   // B*L
#define LSEQ    1024
#define NCH     8      // scan chunks
#define LC      128    // steps per chunk

// ---------- K0: f32 -> bf16 weight conversion ----------
__global__ __launch_bounds__(256) void cvt_bf16_kernel(
    const float* __restrict__ src, ushort* __restrict__ dst, int n4)
{
    int i = blockIdx.x * 256 + threadIdx.x;
    if (i >= n4) return;
    float4 v = *(const float4*)(src + i * 4);
    ushort4 o;
    o.x = f2b(v.x); o.y = f2b(v.y); o.z = f2b(v.z); o.w = f2b(v.w);
    *(ushort4*)(dst + i * 4) = o;
}

// ---------- K1: RMSNorm (f32 in, bf16 h out) + residual f32 copy ----------
__global__ __launch_bounds__(256) void rmsnorm_kernel(
    const float* __restrict__ hs, const float* __restrict__ w,
    ushort* __restrict__ hout, float* __restrict__ resid)
{
    int t = blockIdx.x;
    int tid = threadIdx.x;
    float4 r4 = *(const float4*)(hs + (size_t)t * D_MODEL + tid * 4);
    float s = r4.x * r4.x + r4.y * r4.y + r4.z * r4.z + r4.w * r4.w;
    #pragma unroll
    for (int off = 32; off >= 1; off >>= 1) s += __shfl_xor(s, off);
    __shared__ float red[4];
    int lane = tid & 63, wid = tid >> 6;
    if (lane == 0) red[wid] = s;
    __syncthreads();
    float tot = red[0] + red[1] + red[2] + red[3];
    float inv = 1.0f / (sqrtf(tot) * (1.0f / 32.0f) + 1e-5f);
    float4 w4 = *(const float4*)(w + tid * 4);
    ushort4 o;
    o.x = f2b(w4.x * r4.x * inv);
    o.y = f2b(w4.y * r4.y * inv);
    o.z = f2b(w4.z * r4.z * inv);
    o.w = f2b(w4.w * r4.w * inv);
    *(ushort4*)(hout + (size_t)t * D_MODEL + tid * 4) = o;
    *(float4*)(resid + (size_t)t * D_MODEL + tid * 4) = r4;   // exact copy
}

// ---------- MFMA GEMM: C(MxN) = A(MxK) @ W(NxK)^T, bf16 in, f32 out ----------
__global__ __launch_bounds__(256) void gemm_bt_kernel(
    const ushort* __restrict__ Ag, const ushort* __restrict__ Wg,
    float* __restrict__ Cf, int M, int N, int K)
{
    __shared__ __align__(16) ushort sA[128 * 32];
    __shared__ __align__(16) ushort sB[128 * 32];
    int tid = threadIdx.x;
    int bm = blockIdx.x, bn = blockIdx.y;
    int wid = tid >> 6, lane = tid & 63;
    int wm = (wid >> 1) * 64, wn = (wid & 1) * 64;
    int l16 = lane & 15, q = lane >> 4;

    f32x4 acc[4][4];
    #pragma unroll
    for (int i = 0; i < 4; i++)
        #pragma unroll
        for (int j = 0; j < 4; j++)
            acc[i][j] = (f32x4){0.f, 0.f, 0.f, 0.f};

    const ushort* Abase = Ag + (size_t)bm * 128 * K;
    const ushort* Wbase = Wg + (size_t)bn * 128 * K;

    for (int k0 = 0; k0 < K; k0 += 32) {
        __syncthreads();
        #pragma unroll
        for (int i = tid; i < 512; i += 256) {
            int r = i >> 2, c = (i & 3) << 3;
            *(uint4*)(sA + i * 8) = *(const uint4*)(Abase + (size_t)r * K + k0 + c);
            *(uint4*)(sB + i * 8) = *(const uint4*)(Wbase + (size_t)r * K + k0 + c);
        }
        __syncthreads();
        bf16x8 af[4], bfr[4];
        #pragma unroll
        for (int i = 0; i < 4; i++)
            af[i] = *(const bf16x8*)(sA + (wm + i * 16 + l16) * 32 + q * 8);
        #pragma unroll
        for (int j = 0; j < 4; j++)
            bfr[j] = *(const bf16x8*)(sB + (wn + j * 16 + l16) * 32 + q * 8);
        #pragma unroll
        for (int i = 0; i < 4; i++)
            #pragma unroll
            for (int j = 0; j < 4; j++)
                acc[i][j] = __builtin_amdgcn_mfma_f32_16x16x32_bf16(af[i], bfr[j], acc[i][j], 0, 0, 0);
    }

    int row0 = bm * 128 + wm + q * 4;
    int col0 = bn * 128 + wn + l16;
    #pragma unroll
    for (int i = 0; i < 4; i++)
        #pragma unroll
        for (int j = 0; j < 4; j++)
            #pragma unroll
            for (int r = 0; r < 4; r++)
                Cf[(size_t)(row0 + i * 16 + r) * N + col0 + j * 16] = acc[i][j][r];
}

// ---------- K3: causal depthwise conv (4 taps) + SiLU ----------
__global__ __launch_bounds__(256) void conv_silu_kernel(
    const float* __restrict__ xz, const float* __restrict__ cw,
    const float* __restrict__ cb, float* __restrict__ xc)
{
    int idx = blockIdx.x * 256 + threadIdx.x;     // (token, d) flat over 4M
    int d = idx & (D_INNER - 1);
    int t = idx >> 11;
    int l = t & (LSEQ - 1), b = t >> 10;
    float4 w4 = *(const float4*)(cw + d * 4);
    float acc = cb[d];
    float wk[4] = {w4.x, w4.y, w4.z, w4.w};
    #pragma unroll
    for (int k = 0; k < 4; k++) {
        int ll = l - 3 + k;
        float xv = (ll >= 0) ? xz[(((size_t)(b * LSEQ + ll)) << 12) + d] : 0.f;
        acc += xv * wk[k];
    }
    xc[idx] = acc / (1.f + __expf(-acc));
}

// ---------- K4: per-token x_proj (96 outs) + dt_proj + softplus ----------
__global__ __launch_bounds__(256) void xdbl_dt_kernel(
    const float* __restrict__ xc, const float* __restrict__ xprojw,
    const float* __restrict__ dtw, const float* __restrict__ dtb,
    float* __restrict__ xdbl, float* __restrict__ dtout)
{
    int t = blockIdx.x;
    int tid = threadIdx.x, lane = tid & 63, wid = tid >> 6;
    __shared__ float dtin[DT_RANK];

    const float* xcrow = xc + (size_t)t * D_INNER + lane * 32;
    float xck[32];
    #pragma unroll
    for (int i = 0; i < 32; i++) xck[i] = xcrow[i];

    for (int nn = 0; nn < 24; nn++) {
        int n = wid * 24 + nn;
        const float* wr = xprojw + (size_t)n * D_INNER + lane * 32;
        float s = 0.f;
        #pragma unroll
        for (int i = 0; i < 32; i++) s += xck[i] * wr[i];
        #pragma unroll
        for (int off = 32; off >= 1; off >>= 1) s += __shfl_xor(s, off);
        if (lane == 0) {
            xdbl[(size_t)t * 96 + n] = s;
            if (n < DT_RANK) dtin[n] = s;
        }
    }
    __syncthreads();

    #pragma unroll
    for (int j = 0; j < 8; j++) {
        int d = tid + j * 256;
        const float* w = dtw + (size_t)d * DT_RANK;
        float s = dtb[d];
        #pragma unroll
        for (int r = 0; r < DT_RANK; r++) s += dtin[r] * w[r];
        dtout[(size_t)t * D_INNER + d] = (s > 20.f) ? s : log1pf(__expf(s));
    }
}

// ---------- K5a: scan pass A — per-chunk (aprod, h_local) ----------
// grid: 2048 blocks = b(2) x dgroup(128) x chunk(8); block = 16 d x 16 n
__global__ __launch_bounds__(256) void scan_partA_kernel(
    const float* __restrict__ dt, const float* __restrict__ xc,
    const float* __restrict__ xdbl, const float* __restrict__ Alog,
    float2* __restrict__ chunkAH)
{
    int bid = blockIdx.x;
    int c  = bid & (NCH - 1);
    int dg = (bid >> 3) & 127;
    int b  = bid >> 10;
    int tid = threadIdx.x;
    int n = tid & 15;
    int d = dg * 16 + (tid >> 4);

    float A = -__expf(Alog[d * D_STATE + n]);
    int l0 = c * LC;
    const float* dtp = dt + ((size_t)(b * LSEQ + l0)) * D_INNER + d;
    const float* xcp = xc + ((size_t)(b * LSEQ + l0)) * D_INNER + d;
    const float* Bp  = xdbl + ((size_t)(b * LSEQ + l0)) * 96 + 64 + n;

    float aprod = 1.f, hl = 0.f;
    #pragma unroll 4
    for (int l = 0; l < LC; l++) {
        float dtv = dtp[l * D_INNER];
        float xcv = xcp[l * D_INNER];
        float Bv  = Bp[l * 96];
        float a = __expf(dtv * A);
        hl = a * hl + dtv * xcv * Bv;
        aprod *= a;
    }
    size_t idx = ((size_t)((b * D_INNER + d) * D_STATE + n)) * NCH + c;
    chunkAH[idx] = (float2){aprod, hl};
}

// ---------- K5b: stitch — per-(b,d,n) prefix over 8 chunks ----------
__global__ __launch_bounds__(256) void scan_partB_kernel(
    const float2* __restrict__ chunkAH, float* __restrict__ hinit)
{
    int kk = blockIdx.x * 256 + threadIdx.x;   // 65536 recurrences
    const float2* p = chunkAH + (size_t)kk * NCH;
    float* q = hinit + (size_t)kk * NCH;
    float run = 0.f;
    #pragma unroll
    for (int c = 0; c < NCH; c++) {
        q[c] = run;
        float2 v = p[c];
        run = v.x * run + v.y;
    }
}

// ---------- K5c: scan pass C — recompute with h_init, project, gate ----------
__global__ __launch_bounds__(256) void scan_partC_kernel(
    const float* __restrict__ dt, const float* __restrict__ xc,
    const float* __restrict__ xdbl, const float* __restrict__ xz,
    const float* __restrict__ Alog, const float* __restrict__ Dp,
    const float* __restrict__ hinit, ushort* __restrict__ yg)
{
    int bid = blockIdx.x;
    int c  = bid & (NCH - 1);
    int dg = (bid >> 3) & 127;
    int b  = bid >> 10;
    int tid = threadIdx.x;
    int n = tid & 15;
    int d = dg * 16 + (tid >> 4);

    float A = -__expf(Alog[d * D_STATE + n]);
    float Dd = Dp[d];
    int l0 = c * LC;
    const float* dtp = dt + ((size_t)(b * LSEQ + l0)) * D_INNER + d;
    const float* xcp = xc + ((size_t)(b * LSEQ + l0)) * D_INNER + d;
    const float* Bp  = xdbl + ((size_t)(b * LSEQ + l0)) * 96 + 64 + n;
    const float* Cp  = Bp + 16;
    const float* zp  = xz + ((size_t)(b * LSEQ + l0)) * (2 * D_INNER) + D_INNER + d;
    ushort* yp = yg + ((size_t)(b * LSEQ + l0)) * D_INNER + d;

    float h = hinit[((size_t)((b * D_INNER + d) * D_STATE + n)) * NCH + c];

    #pragma unroll 4
    for (int l = 0; l < LC; l++) {
        float dtv = dtp[l * D_INNER];
        float xcv = xcp[l * D_INNER];
        float Bv  = Bp[l * 96];
        float Cv  = Cp[l * 96];
        float a = __expf(dtv * A);
        h = a * h + dtv * xcv * Bv;
        float p = h * Cv;
        p += __shfl_xor(p, 1);
        p += __shfl_xor(p, 2);
        p += __shfl_xor(p, 4);
        p += __shfl_xor(p, 8);
        if (n == 0) {
            float zv = zp[l * (2 * D_INNER)];
            float y = p + Dd * xcv;
            float sz = zv / (1.f + __expf(-zv));
            yp[(size_t)l * D_INNER] = f2b(y * sz);
        }
    }
}

extern "C" void kernel_launch(void* const* d_in, const int* in_sizes, int n_in,
                              void* d_out, int out_size, void* d_ws, size_t ws_size,
                              hipStream_t stream)
{
    const float* hs      = (const float*)d_in[0];
    const float* norm_w  = (const float*)d_in[1];
    const float* inproj  = (const float*)d_in[2];
    const float* convw   = (const float*)d_in[3];
    const float* convb   = (const float*)d_in[4];
    const float* xprojw  = (const float*)d_in[5];
    const float* dtw     = (const float*)d_in[6];
    const float* dtb     = (const float*)d_in[7];
    const float* alog    = (const float*)d_in[8];
    const float* dvec    = (const float*)d_in[9];
    const float* outproj = (const float*)d_in[10];

    float* out_main  = (float*)d_out;                        // (B,L,D_MODEL) f32
    float* out_resid = (float*)d_out + (size_t)NTOK * D_MODEL;

    char* ws = (char*)d_ws;
    float*  xz_f32  = (float*)(ws);                          // 2048*4096 f32  (32MB)
    float*  xc_f32  = (float*)(ws + 33554432);               // 2048*2048 f32  (16MB)
    float*  dt_f32  = (float*)(ws + 50331648);               // 2048*2048 f32  (16MB)
    float*  xdbl    = (float*)(ws + 67108864);               // 2048*96 f32    (768KB)
    ushort* h_bf16  = (ushort*)(ws + 67895296);              // 2048*1024 bf16 (4MB)
    ushort* yg_bf16 = (ushort*)(ws + 72089600);              // 2048*2048 bf16 (8MB)
    ushort* wIn     = (ushort*)(ws + 80478208);              // 4096*1024 bf16 (8MB) — dead after K2
    ushort* wOut    = (ushort*)(ws + 88866816);              // 1024*2048 bf16 (4MB)
    // scan scratch reuses the dead wIn region (fully rewritten before read each call)
    float2* chunkAH = (float2*)(ws + 80478208);              // 65536*8 float2 (4MB)
    float*  hinit   = (float*)(ws + 84672512);               // 65536*8 f32    (2MB)

    // K0: convert GEMM weights to bf16
    cvt_bf16_kernel<<<(2 * D_INNER * D_MODEL / 4 + 255) / 256, 256, 0, stream>>>(
        inproj, wIn, 2 * D_INNER * D_MODEL / 4);
    cvt_bf16_kernel<<<(D_MODEL * D_INNER / 4 + 255) / 256, 256, 0, stream>>>(
        outproj, wOut, D_MODEL * D_INNER / 4);

    // K1: RMSNorm + residual copy
    rmsnorm_kernel<<<NTOK, 256, 0, stream>>>(hs, norm_w, h_bf16, out_resid);

    // K2: xz = h @ in_proj_w^T  (2048 x 4096 x 1024) -> f32
    gemm_bt_kernel<<<dim3(NTOK / 128, (2 * D_INNER) / 128), 256, 0, stream>>>(
        h_bf16, wIn, xz_f32, NTOK, 2 * D_INNER, D_MODEL);

    // K3: conv + SiLU
    conv_silu_kernel<<<(NTOK * D_INNER) / 256, 256, 0, stream>>>(
        xz_f32, convw, convb, xc_f32);

    // K4: x_dbl + dt
    xdbl_dt_kernel<<<NTOK, 256, 0, stream>>>(xc_f32, xprojw, dtw, dtb, xdbl, dt_f32);

    // K5: chunked parallel scan (A: local scans, B: stitch, C: finalize+gate)
    scan_partA_kernel<<<2048, 256, 0, stream>>>(dt_f32, xc_f32, xdbl, alog, chunkAH);
    scan_partB_kernel<<<256, 256, 0, stream>>>(chunkAH, hinit);
    scan_partC_kernel<<<2048, 256, 0, stream>>>(dt_f32, xc_f32, xdbl, xz_f32,
                                                alog, dvec, hinit, yg_bf16);

    // K6: out = yg @ out_proj_w^T  (2048 x 1024 x 2048) -> f32 into d_out
    gemm_bt_kernel<<<dim3(NTOK / 128, D_MODEL / 128), 256, 0, stream>>>(
        yg_bf16, wOut, out_main, NTOK, D_MODEL, D_INNER);
}

// Round 4
// 440.027 us; speedup vs baseline: 1.9823x; 1.4652x over previous
//
#include <hip/hip_runtime.h>

// ---------- common helpers ----------
typedef __bf16 bf16x8 __attribute__((ext_vector_type(8)));
typedef float f32x4 __attribute__((ext_vector_type(4)));

__device__ __forceinline__ ushort f2b(float f) {
    union { float f; unsigned int i; } v;
    v.f = f;
    unsigned int x = v.i;
    unsigned int r = (x + 0x7fffu + ((x >> 16) & 1u)) >> 16;
    return (ushort)r;
}

#define D_MODEL 1024
#define D_INNER 2048
#define D_STATE 16
#define DT_RANK 64
#define NTOK    2048   // B*L
#define LSEQ    1024
#define NCH     8      // scan chunks
#define LC      128    // steps per chunk

// ---------- K0: f32 -> bf16 conversion ----------
__global__ __launch_bounds__(256) void cvt_bf16_kernel(
    const float* __restrict__ src, ushort* __restrict__ dst, int n4)
{
    int i = blockIdx.x * 256 + threadIdx.x;
    if (i >= n4) return;
    float4 v = *(const float4*)(src + i * 4);
    ushort4 o;
    o.x = f2b(v.x); o.y = f2b(v.y); o.z = f2b(v.z); o.w = f2b(v.w);
    *(ushort4*)(dst + i * 4) = o;
}

// ---------- K1: RMSNorm (f32 in, bf16 h out) + residual f32 copy ----------
__global__ __launch_bounds__(256) void rmsnorm_kernel(
    const float* __restrict__ hs, const float* __restrict__ w,
    ushort* __restrict__ hout, float* __restrict__ resid)
{
    int t = blockIdx.x;
    int tid = threadIdx.x;
    float4 r4 = *(const float4*)(hs + (size_t)t * D_MODEL + tid * 4);
    float s = r4.x * r4.x + r4.y * r4.y + r4.z * r4.z + r4.w * r4.w;
    #pragma unroll
    for (int off = 32; off >= 1; off >>= 1) s += __shfl_xor(s, off);
    __shared__ float red[4];
    int lane = tid & 63, wid = tid >> 6;
    if (lane == 0) red[wid] = s;
    __syncthreads();
    float tot = red[0] + red[1] + red[2] + red[3];
    float inv = 1.0f / (sqrtf(tot) * (1.0f / 32.0f) + 1e-5f);
    float4 w4 = *(const float4*)(w + tid * 4);
    ushort4 o;
    o.x = f2b(w4.x * r4.x * inv);
    o.y = f2b(w4.y * r4.y * inv);
    o.z = f2b(w4.z * r4.z * inv);
    o.w = f2b(w4.w * r4.w * inv);
    *(ushort4*)(hout + (size_t)t * D_MODEL + tid * 4) = o;
    *(float4*)(resid + (size_t)t * D_MODEL + tid * 4) = r4;   // exact copy
}

// ---------- MFMA GEMM: C(MxN) = A(MxK) @ W(NxK)^T, bf16 in, f32 out ----------
__global__ __launch_bounds__(256) void gemm_bt_kernel(
    const ushort* __restrict__ Ag, const ushort* __restrict__ Wg,
    float* __restrict__ Cf, int M, int N, int K)
{
    __shared__ __align__(16) ushort sA[128 * 32];
    __shared__ __align__(16) ushort sB[128 * 32];
    int tid = threadIdx.x;
    int bm = blockIdx.x, bn = blockIdx.y;
    int wid = tid >> 6, lane = tid & 63;
    int wm = (wid >> 1) * 64, wn = (wid & 1) * 64;
    int l16 = lane & 15, q = lane >> 4;

    f32x4 acc[4][4];
    #pragma unroll
    for (int i = 0; i < 4; i++)
        #pragma unroll
        for (int j = 0; j < 4; j++)
            acc[i][j] = (f32x4){0.f, 0.f, 0.f, 0.f};

    const ushort* Abase = Ag + (size_t)bm * 128 * K;
    const ushort* Wbase = Wg + (size_t)bn * 128 * K;

    for (int k0 = 0; k0 < K; k0 += 32) {
        __syncthreads();
        #pragma unroll
        for (int i = tid; i < 512; i += 256) {
            int r = i >> 2, c = (i & 3) << 3;
            *(uint4*)(sA + i * 8) = *(const uint4*)(Abase + (size_t)r * K + k0 + c);
            *(uint4*)(sB + i * 8) = *(const uint4*)(Wbase + (size_t)r * K + k0 + c);
        }
        __syncthreads();
        bf16x8 af[4], bfr[4];
        #pragma unroll
        for (int i = 0; i < 4; i++)
            af[i] = *(const bf16x8*)(sA + (wm + i * 16 + l16) * 32 + q * 8);
        #pragma unroll
        for (int j = 0; j < 4; j++)
            bfr[j] = *(const bf16x8*)(sB + (wn + j * 16 + l16) * 32 + q * 8);
        #pragma unroll
        for (int i = 0; i < 4; i++)
            #pragma unroll
            for (int j = 0; j < 4; j++)
                acc[i][j] = __builtin_amdgcn_mfma_f32_16x16x32_bf16(af[i], bfr[j], acc[i][j], 0, 0, 0);
    }

    int row0 = bm * 128 + wm + q * 4;
    int col0 = bn * 128 + wn + l16;
    #pragma unroll
    for (int i = 0; i < 4; i++)
        #pragma unroll
        for (int j = 0; j < 4; j++)
            #pragma unroll
            for (int r = 0; r < 4; r++)
                Cf[(size_t)(row0 + i * 16 + r) * N + col0 + j * 16] = acc[i][j][r];
}

// ---------- K3: causal depthwise conv (4 taps) + SiLU (f32 + bf16 out) ----------
__global__ __launch_bounds__(256) void conv_silu_kernel(
    const float* __restrict__ xz, const float* __restrict__ cw,
    const float* __restrict__ cb, float* __restrict__ xc, ushort* __restrict__ xcb)
{
    int idx = blockIdx.x * 256 + threadIdx.x;     // (token, d) flat over 4M
    int d = idx & (D_INNER - 1);
    int t = idx >> 11;
    int l = t & (LSEQ - 1), b = t >> 10;
    float4 w4 = *(const float4*)(cw + d * 4);
    float acc = cb[d];
    float wk[4] = {w4.x, w4.y, w4.z, w4.w};
    #pragma unroll
    for (int k = 0; k < 4; k++) {
        int ll = l - 3 + k;
        float xv = (ll >= 0) ? xz[(((size_t)(b * LSEQ + ll)) << 12) + d] : 0.f;
        acc += xv * wk[k];
    }
    float sg = acc / (1.f + __expf(-acc));
    xc[idx] = sg;
    xcb[idx] = f2b(sg);
}

// ---------- K4a: x_dbl(2048x96) = xc_bf16 @ x_proj_w^T via MFMA ----------
// grid 16 blocks (M/128); wave w handles rows w*32..w*32+31, all 96 cols
__global__ __launch_bounds__(256) void xproj_gemm_kernel(
    const ushort* __restrict__ xcb, const ushort* __restrict__ wq,
    float* __restrict__ xdbl, ushort* __restrict__ xdbl64)
{
    __shared__ __align__(16) ushort sA[128 * 32];
    __shared__ __align__(16) ushort sB[96 * 32];
    int tid = threadIdx.x;
    int bm = blockIdx.x;
    int wid = tid >> 6, lane = tid & 63;
    int wm = wid * 32;
    int l16 = lane & 15, q = lane >> 4;

    f32x4 acc[2][6];
    #pragma unroll
    for (int i = 0; i < 2; i++)
        #pragma unroll
        for (int j = 0; j < 6; j++)
            acc[i][j] = (f32x4){0.f, 0.f, 0.f, 0.f};

    const ushort* Abase = xcb + (size_t)bm * 128 * D_INNER;

    for (int k0 = 0; k0 < D_INNER; k0 += 32) {
        __syncthreads();
        #pragma unroll
        for (int i = tid; i < 512; i += 256) {
            int r = i >> 2, c = (i & 3) << 3;
            *(uint4*)(sA + i * 8) = *(const uint4*)(Abase + (size_t)r * D_INNER + k0 + c);
        }
        for (int i = tid; i < 384; i += 256) {
            int r = i >> 2, c = (i & 3) << 3;
            *(uint4*)(sB + i * 8) = *(const uint4*)(wq + (size_t)r * D_INNER + k0 + c);
        }
        __syncthreads();
        bf16x8 af[2], bfr[6];
        #pragma unroll
        for (int i = 0; i < 2; i++)
            af[i] = *(const bf16x8*)(sA + (wm + i * 16 + l16) * 32 + q * 8);
        #pragma unroll
        for (int j = 0; j < 6; j++)
            bfr[j] = *(const bf16x8*)(sB + (j * 16 + l16) * 32 + q * 8);
        #pragma unroll
        for (int i = 0; i < 2; i++)
            #pragma unroll
            for (int j = 0; j < 6; j++)
                acc[i][j] = __builtin_amdgcn_mfma_f32_16x16x32_bf16(af[i], bfr[j], acc[i][j], 0, 0, 0);
    }

    int row0 = bm * 128 + wm + q * 4;
    #pragma unroll
    for (int i = 0; i < 2; i++)
        #pragma unroll
        for (int j = 0; j < 6; j++)
            #pragma unroll
            for (int r = 0; r < 4; r++) {
                int row = row0 + i * 16 + r;
                int col = j * 16 + l16;
                float v = acc[i][j][r];
                xdbl[(size_t)row * 96 + col] = v;
                if (col < DT_RANK) xdbl64[(size_t)row * DT_RANK + col] = f2b(v);
            }
}

// ---------- K4b: dt = softplus(xdbl64 @ dt_proj_w^T + b) via MFMA ----------
// K=64, single LDS stage (stride 72 to break bank aliasing), 2 k-steps
__global__ __launch_bounds__(256) void dt_gemm_kernel(
    const ushort* __restrict__ xd64, const ushort* __restrict__ dtwq,
    const float* __restrict__ dtb, float* __restrict__ dtout)
{
    __shared__ __align__(16) ushort sA[128 * 72];
    __shared__ __align__(16) ushort sB[128 * 72];
    int tid = threadIdx.x;
    int bm = blockIdx.x, bn = blockIdx.y;
    int wid = tid >> 6, lane = tid & 63;
    int wm = (wid >> 1) * 64, wn = (wid & 1) * 64;
    int l16 = lane & 15, q = lane >> 4;

    const ushort* Abase = xd64 + (size_t)bm * 128 * DT_RANK;
    const ushort* Bbase = dtwq + (size_t)bn * 128 * DT_RANK;
    #pragma unroll
    for (int i = tid; i < 1024; i += 256) {
        int r = i >> 3, c = (i & 7) << 3;
        *(uint4*)(sA + r * 72 + c) = *(const uint4*)(Abase + (size_t)r * DT_RANK + c);
        *(uint4*)(sB + r * 72 + c) = *(const uint4*)(Bbase + (size_t)r * DT_RANK + c);
    }
    __syncthreads();

    f32x4 acc[4][4];
    #pragma unroll
    for (int i = 0; i < 4; i++)
        #pragma unroll
        for (int j = 0; j < 4; j++)
            acc[i][j] = (f32x4){0.f, 0.f, 0.f, 0.f};

    #pragma unroll
    for (int ks = 0; ks < 2; ks++) {
        bf16x8 af[4], bfr[4];
        #pragma unroll
        for (int i = 0; i < 4; i++)
            af[i] = *(const bf16x8*)(sA + (wm + i * 16 + l16) * 72 + ks * 32 + q * 8);
        #pragma unroll
        for (int j = 0; j < 4; j++)
            bfr[j] = *(const bf16x8*)(sB + (wn + j * 16 + l16) * 72 + ks * 32 + q * 8);
        #pragma unroll
        for (int i = 0; i < 4; i++)
            #pragma unroll
            for (int j = 0; j < 4; j++)
                acc[i][j] = __builtin_amdgcn_mfma_f32_16x16x32_bf16(af[i], bfr[j], acc[i][j], 0, 0, 0);
    }

    int row0 = bm * 128 + wm + q * 4;
    int col0 = bn * 128 + wn + l16;
    #pragma unroll
    for (int j = 0; j < 4; j++) {
        int col = col0 + j * 16;
        float bias = dtb[col];
        #pragma unroll
        for (int i = 0; i < 4; i++)
            #pragma unroll
            for (int r = 0; r < 4; r++) {
                float s = acc[i][j][r] + bias;
                dtout[(size_t)(row0 + i * 16 + r) * D_INNER + col] =
                    (s > 20.f) ? s : log1pf(__expf(s));
            }
    }
}

// ---------- K5a: scan pass A — per-chunk (aprod, h_local) ----------
__global__ __launch_bounds__(256) void scan_partA_kernel(
    const float* __restrict__ dt, const float* __restrict__ xc,
    const float* __restrict__ xdbl, const float* __restrict__ Alog,
    float2* __restrict__ chunkAH)
{
    int bid = blockIdx.x;
    int c  = bid & (NCH - 1);
    int dg = (bid >> 3) & 127;
    int b  = bid >> 10;
    int tid = threadIdx.x;
    int n = tid & 15;
    int d = dg * 16 + (tid >> 4);

    float A = -__expf(Alog[d * D_STATE + n]);
    int l0 = c * LC;
    const float* dtp = dt + ((size_t)(b * LSEQ + l0)) * D_INNER + d;
    const float* xcp = xc + ((size_t)(b * LSEQ + l0)) * D_INNER + d;
    const float* Bp  = xdbl + ((size_t)(b * LSEQ + l0)) * 96 + 64 + n;

    float aprod = 1.f, hl = 0.f;
    #pragma unroll 4
    for (int l = 0; l < LC; l++) {
        float dtv = dtp[l * D_INNER];
        float xcv = xcp[l * D_INNER];
        float Bv  = Bp[l * 96];
        float a = __expf(dtv * A);
        hl = a * hl + dtv * xcv * Bv;
        aprod *= a;
    }
    size_t idx = ((size_t)((b * D_INNER + d) * D_STATE + n)) * NCH + c;
    chunkAH[idx] = (float2){aprod, hl};
}

// ---------- K5b: stitch ----------
__global__ __launch_bounds__(256) void scan_partB_kernel(
    const float2* __restrict__ chunkAH, float* __restrict__ hinit)
{
    int kk = blockIdx.x * 256 + threadIdx.x;   // 65536 recurrences
    const float2* p = chunkAH + (size_t)kk * NCH;
    float* q = hinit + (size_t)kk * NCH;
    float run = 0.f;
    #pragma unroll
    for (int c = 0; c < NCH; c++) {
        q[c] = run;
        float2 v = p[c];
        run = v.x * run + v.y;
    }
}

// ---------- K5c: scan pass C — recompute with h_init, project, gate ----------
__global__ __launch_bounds__(256) void scan_partC_kernel(
    const float* __restrict__ dt, const float* __restrict__ xc,
    const float* __restrict__ xdbl, const float* __restrict__ xz,
    const float* __restrict__ Alog, const float* __restrict__ Dp,
    const float* __restrict__ hinit, ushort* __restrict__ yg)
{
    int bid = blockIdx.x;
    int c  = bid & (NCH - 1);
    int dg = (bid >> 3) & 127;
    int b  = bid >> 10;
    int tid = threadIdx.x;
    int n = tid & 15;
    int d = dg * 16 + (tid >> 4);

    float A = -__expf(Alog[d * D_STATE + n]);
    float Dd = Dp[d];
    int l0 = c * LC;
    const float* dtp = dt + ((size_t)(b * LSEQ + l0)) * D_INNER + d;
    const float* xcp = xc + ((size_t)(b * LSEQ + l0)) * D_INNER + d;
    const float* Bp  = xdbl + ((size_t)(b * LSEQ + l0)) * 96 + 64 + n;
    const float* Cp  = Bp + 16;
    const float* zp  = xz + ((size_t)(b * LSEQ + l0)) * (2 * D_INNER) + D_INNER + d;
    ushort* yp = yg + ((size_t)(b * LSEQ + l0)) * D_INNER + d;

    float h = hinit[((size_t)((b * D_INNER + d) * D_STATE + n)) * NCH + c];

    #pragma unroll 4
    for (int l = 0; l < LC; l++) {
        float dtv = dtp[l * D_INNER];
        float xcv = xcp[l * D_INNER];
        float Bv  = Bp[l * 96];
        float Cv  = Cp[l * 96];
        float a = __expf(dtv * A);
        h = a * h + dtv * xcv * Bv;
        float p = h * Cv;
        p += __shfl_xor(p, 1);
        p += __shfl_xor(p, 2);
        p += __shfl_xor(p, 4);
        p += __shfl_xor(p, 8);
        if (n == 0) {
            float zv = zp[l * (2 * D_INNER)];
            float y = p + Dd * xcv;
            float sz = zv / (1.f + __expf(-zv));
            yp[(size_t)l * D_INNER] = f2b(y * sz);
        }
    }
}

extern "C" void kernel_launch(void* const* d_in, const int* in_sizes, int n_in,
                              void* d_out, int out_size, void* d_ws, size_t ws_size,
                              hipStream_t stream)
{
    const float* hs      = (const float*)d_in[0];
    const float* norm_w  = (const float*)d_in[1];
    const float* inproj  = (const float*)d_in[2];
    const float* convw   = (const float*)d_in[3];
    const float* convb   = (const float*)d_in[4];
    const float* xprojw  = (const float*)d_in[5];
    const float* dtw     = (const float*)d_in[6];
    const float* dtb     = (const float*)d_in[7];
    const float* alog    = (const float*)d_in[8];
    const float* dvec    = (const float*)d_in[9];
    const float* outproj = (const float*)d_in[10];

    float* out_main  = (float*)d_out;                        // (B,L,D_MODEL) f32
    float* out_resid = (float*)d_out + (size_t)NTOK * D_MODEL;

    char* ws = (char*)d_ws;
    float*  xz_f32  = (float*)(ws);                          // 32MB
    float*  xc_f32  = (float*)(ws + 33554432);               // 16MB
    float*  dt_f32  = (float*)(ws + 50331648);               // 16MB
    float*  xdbl    = (float*)(ws + 67108864);               // 768KB
    ushort* h_bf16  = (ushort*)(ws + 67895296);              // 4MB — dead after K2
    ushort* yg_bf16 = (ushort*)(ws + 72089600);              // 8MB — written K5c
    ushort* wIn     = (ushort*)(ws + 80478208);              // 8MB — dead after K2
    ushort* wOut    = (ushort*)(ws + 88866816);              // 4MB
    // overlays (lifetimes disjoint from hosts):
    ushort* xpw_b   = (ushort*)(ws + 67895296);              // 96*2048 bf16 (384KB) in h_bf16 region
    ushort* dtw_b   = (ushort*)(ws + 68288512);              // 2048*64 bf16 (256KB)
    ushort* xd64_b  = (ushort*)(ws + 68550656);              // 2048*64 bf16 (256KB)
    ushort* xc_bf16 = (ushort*)(ws + 72089600);              // 8MB in yg region (dead before K5c)
    float2* chunkAH = (float2*)(ws + 80478208);              // 4MB in wIn region
    float*  hinit   = (float*)(ws + 84672512);               // 2MB

    // weight conversions for the big GEMMs
    cvt_bf16_kernel<<<(2 * D_INNER * D_MODEL / 4 + 255) / 256, 256, 0, stream>>>(
        inproj, wIn, 2 * D_INNER * D_MODEL / 4);
    cvt_bf16_kernel<<<(D_MODEL * D_INNER / 4 + 255) / 256, 256, 0, stream>>>(
        outproj, wOut, D_MODEL * D_INNER / 4);

    // K1: RMSNorm + residual copy
    rmsnorm_kernel<<<NTOK, 256, 0, stream>>>(hs, norm_w, h_bf16, out_resid);

    // K2: xz = h @ in_proj_w^T
    gemm_bt_kernel<<<dim3(NTOK / 128, (2 * D_INNER) / 128), 256, 0, stream>>>(
        h_bf16, wIn, xz_f32, NTOK, 2 * D_INNER, D_MODEL);

    // small weight conversions (into h_bf16 region — free after K2)
    cvt_bf16_kernel<<<(96 * D_INNER / 4 + 255) / 256, 256, 0, stream>>>(
        xprojw, xpw_b, 96 * D_INNER / 4);
    cvt_bf16_kernel<<<(D_INNER * DT_RANK / 4 + 255) / 256, 256, 0, stream>>>(
        dtw, dtw_b, D_INNER * DT_RANK / 4);

    // K3: conv + SiLU (f32 + bf16)
    conv_silu_kernel<<<(NTOK * D_INNER) / 256, 256, 0, stream>>>(
        xz_f32, convw, convb, xc_f32, xc_bf16);

    // K4a: x_dbl GEMM (MFMA)
    xproj_gemm_kernel<<<NTOK / 128, 256, 0, stream>>>(xc_bf16, xpw_b, xdbl, xd64_b);

    // K4b: dt GEMM (MFMA) + bias + softplus
    dt_gemm_kernel<<<dim3(NTOK / 128, D_INNER / 128), 256, 0, stream>>>(
        xd64_b, dtw_b, dtb, dt_f32);

    // K5: chunked parallel scan
    scan_partA_kernel<<<2048, 256, 0, stream>>>(dt_f32, xc_f32, xdbl, alog, chunkAH);
    scan_partB_kernel<<<256, 256, 0, stream>>>(chunkAH, hinit);
    scan_partC_kernel<<<2048, 256, 0, stream>>>(dt_f32, xc_f32, xdbl, xz_f32,
                                                alog, dvec, hinit, yg_bf16);

    // K6: out = yg @ out_proj_w^T
    gemm_bt_kernel<<<dim3(NTOK / 128, D_MODEL / 128), 256, 0, stream>>>(
        yg_bf16, wOut, out_main, NTOK, D_MODEL, D_INNER);
}

// Round 5
// 430.260 us; speedup vs baseline: 2.0273x; 1.0227x over previous
//
#include <hip/hip_runtime.h>

// ---------- common helpers ----------
typedef __bf16 bf16x8 __attribute__((ext_vector_type(8)));
typedef float f32x4 __attribute__((ext_vector_type(4)));

__device__ __forceinline__ float b2f(ushort u) {
    union { unsigned int i; float f; } v;
    v.i = ((unsigned int)u) << 16;
    return v.f;
}
__device__ __forceinline__ ushort f2b(float f) {
    union { float f; unsigned int i; } v;
    v.f = f;
    unsigned int x = v.i;
    unsigned int r = (x + 0x7fffu + ((x >> 16) & 1u)) >> 16;
    return (ushort)r;
}

#define D_MODEL 1024
#define D_INNER 2048
#define D_STATE 16
#define DT_RANK 64
#define NTOK    2048   // B*L
#define LSEQ    1024
#define NCH     8      // scan chunks
#define LC      128    // steps per chunk

// ---------- K0: f32 -> bf16 conversion ----------
__global__ __launch_bounds__(256) void cvt_bf16_kernel(
    const float* __restrict__ src, ushort* __restrict__ dst, int n4)
{
    int i = blockIdx.x * 256 + threadIdx.x;
    if (i >= n4) return;
    float4 v = *(const float4*)(src + i * 4);
    ushort4 o;
    o.x = f2b(v.x); o.y = f2b(v.y); o.z = f2b(v.z); o.w = f2b(v.w);
    *(ushort4*)(dst + i * 4) = o;
}

// ---------- K1: RMSNorm (f32 in, bf16 h out) + residual f32 copy ----------
__global__ __launch_bounds__(256) void rmsnorm_kernel(
    const float* __restrict__ hs, const float* __restrict__ w,
    ushort* __restrict__ hout, float* __restrict__ resid)
{
    int t = blockIdx.x;
    int tid = threadIdx.x;
    float4 r4 = *(const float4*)(hs + (size_t)t * D_MODEL + tid * 4);
    float s = r4.x * r4.x + r4.y * r4.y + r4.z * r4.z + r4.w * r4.w;
    #pragma unroll
    for (int off = 32; off >= 1; off >>= 1) s += __shfl_xor(s, off);
    __shared__ float red[4];
    int lane = tid & 63, wid = tid >> 6;
    if (lane == 0) red[wid] = s;
    __syncthreads();
    float tot = red[0] + red[1] + red[2] + red[3];
    float inv = 1.0f / (sqrtf(tot) * (1.0f / 32.0f) + 1e-5f);
    float4 w4 = *(const float4*)(w + tid * 4);
    ushort4 o;
    o.x = f2b(w4.x * r4.x * inv);
    o.y = f2b(w4.y * r4.y * inv);
    o.z = f2b(w4.z * r4.z * inv);
    o.w = f2b(w4.w * r4.w * inv);
    *(ushort4*)(hout + (size_t)t * D_MODEL + tid * 4) = o;
    *(float4*)(resid + (size_t)t * D_MODEL + tid * 4) = r4;   // exact copy
}

// ---------- MFMA GEMM: C(MxN) = A(MxK) @ W(NxK)^T, bf16 in, f32 out ----------
__global__ __launch_bounds__(256) void gemm_bt_kernel(
    const ushort* __restrict__ Ag, const ushort* __restrict__ Wg,
    float* __restrict__ Cf, int M, int N, int K)
{
    __shared__ __align__(16) ushort sA[128 * 32];
    __shared__ __align__(16) ushort sB[128 * 32];
    int tid = threadIdx.x;
    int bm = blockIdx.x, bn = blockIdx.y;
    int wid = tid >> 6, lane = tid & 63;
    int wm = (wid >> 1) * 64, wn = (wid & 1) * 64;
    int l16 = lane & 15, q = lane >> 4;

    f32x4 acc[4][4];
    #pragma unroll
    for (int i = 0; i < 4; i++)
        #pragma unroll
        for (int j = 0; j < 4; j++)
            acc[i][j] = (f32x4){0.f, 0.f, 0.f, 0.f};

    const ushort* Abase = Ag + (size_t)bm * 128 * K;
    const ushort* Wbase = Wg + (size_t)bn * 128 * K;

    for (int k0 = 0; k0 < K; k0 += 32) {
        __syncthreads();
        #pragma unroll
        for (int i = tid; i < 512; i += 256) {
            int r = i >> 2, c = (i & 3) << 3;
            *(uint4*)(sA + i * 8) = *(const uint4*)(Abase + (size_t)r * K + k0 + c);
            *(uint4*)(sB + i * 8) = *(const uint4*)(Wbase + (size_t)r * K + k0 + c);
        }
        __syncthreads();
        bf16x8 af[4], bfr[4];
        #pragma unroll
        for (int i = 0; i < 4; i++)
            af[i] = *(const bf16x8*)(sA + (wm + i * 16 + l16) * 32 + q * 8);
        #pragma unroll
        for (int j = 0; j < 4; j++)
            bfr[j] = *(const bf16x8*)(sB + (wn + j * 16 + l16) * 32 + q * 8);
        #pragma unroll
        for (int i = 0; i < 4; i++)
            #pragma unroll
            for (int j = 0; j < 4; j++)
                acc[i][j] = __builtin_amdgcn_mfma_f32_16x16x32_bf16(af[i], bfr[j], acc[i][j], 0, 0, 0);
    }

    int row0 = bm * 128 + wm + q * 4;
    int col0 = bn * 128 + wn + l16;
    #pragma unroll
    for (int i = 0; i < 4; i++)
        #pragma unroll
        for (int j = 0; j < 4; j++)
            #pragma unroll
            for (int r = 0; r < 4; r++)
                Cf[(size_t)(row0 + i * 16 + r) * N + col0 + j * 16] = acc[i][j][r];
}

// ---------- K3: causal depthwise conv (4 taps) + SiLU (f32 + bf16 out) ----------
__global__ __launch_bounds__(256) void conv_silu_kernel(
    const float* __restrict__ xz, const float* __restrict__ cw,
    const float* __restrict__ cb, float* __restrict__ xc, ushort* __restrict__ xcb)
{
    int idx = blockIdx.x * 256 + threadIdx.x;     // (token, d) flat over 4M
    int d = idx & (D_INNER - 1);
    int t = idx >> 11;
    int l = t & (LSEQ - 1), b = t >> 10;
    float4 w4 = *(const float4*)(cw + d * 4);
    float acc = cb[d];
    float wk[4] = {w4.x, w4.y, w4.z, w4.w};
    #pragma unroll
    for (int k = 0; k < 4; k++) {
        int ll = l - 3 + k;
        float xv = (ll >= 0) ? xz[(((size_t)(b * LSEQ + ll)) << 12) + d] : 0.f;
        acc += xv * wk[k];
    }
    float sg = acc / (1.f + __expf(-acc));
    xc[idx] = sg;
    xcb[idx] = f2b(sg);
}

// ---------- K4a: x_dbl(2048x96) = xc_bf16 @ x_proj_w^T via MFMA ----------
__global__ __launch_bounds__(256) void xproj_gemm_kernel(
    const ushort* __restrict__ xcb, const ushort* __restrict__ wq,
    float* __restrict__ xdbl, ushort* __restrict__ xdbl64)
{
    __shared__ __align__(16) ushort sA[128 * 32];
    __shared__ __align__(16) ushort sB[96 * 32];
    int tid = threadIdx.x;
    int bm = blockIdx.x;
    int wid = tid >> 6, lane = tid & 63;
    int wm = wid * 32;
    int l16 = lane & 15, q = lane >> 4;

    f32x4 acc[2][6];
    #pragma unroll
    for (int i = 0; i < 2; i++)
        #pragma unroll
        for (int j = 0; j < 6; j++)
            acc[i][j] = (f32x4){0.f, 0.f, 0.f, 0.f};

    const ushort* Abase = xcb + (size_t)bm * 128 * D_INNER;

    for (int k0 = 0; k0 < D_INNER; k0 += 32) {
        __syncthreads();
        #pragma unroll
        for (int i = tid; i < 512; i += 256) {
            int r = i >> 2, c = (i & 3) << 3;
            *(uint4*)(sA + i * 8) = *(const uint4*)(Abase + (size_t)r * D_INNER + k0 + c);
        }
        for (int i = tid; i < 384; i += 256) {
            int r = i >> 2, c = (i & 3) << 3;
            *(uint4*)(sB + i * 8) = *(const uint4*)(wq + (size_t)r * D_INNER + k0 + c);
        }
        __syncthreads();
        bf16x8 af[2], bfr[6];
        #pragma unroll
        for (int i = 0; i < 2; i++)
            af[i] = *(const bf16x8*)(sA + (wm + i * 16 + l16) * 32 + q * 8);
        #pragma unroll
        for (int j = 0; j < 6; j++)
            bfr[j] = *(const bf16x8*)(sB + (j * 16 + l16) * 32 + q * 8);
        #pragma unroll
        for (int i = 0; i < 2; i++)
            #pragma unroll
            for (int j = 0; j < 6; j++)
                acc[i][j] = __builtin_amdgcn_mfma_f32_16x16x32_bf16(af[i], bfr[j], acc[i][j], 0, 0, 0);
    }

    int row0 = bm * 128 + wm + q * 4;
    #pragma unroll
    for (int i = 0; i < 2; i++)
        #pragma unroll
        for (int j = 0; j < 6; j++)
            #pragma unroll
            for (int r = 0; r < 4; r++) {
                int row = row0 + i * 16 + r;
                int col = j * 16 + l16;
                float v = acc[i][j][r];
                xdbl[(size_t)row * 96 + col] = v;
                if (col < DT_RANK) xdbl64[(size_t)row * DT_RANK + col] = f2b(v);
            }
}

// ---------- K4b: dt = softplus(xdbl64 @ dt_proj_w^T + b) -> bf16, coalesced ----------
// 64x64 tiles, grid (32,32)=1024 blocks, LDS-staged bf16 output
__global__ __launch_bounds__(256) void dt_gemm_kernel(
    const ushort* __restrict__ xd64, const ushort* __restrict__ dtwq,
    const float* __restrict__ dtb, ushort* __restrict__ dtout)
{
    __shared__ __align__(16) ushort sA[64 * 72];   // also reused as bf16 output stage
    __shared__ __align__(16) ushort sB[64 * 72];
    int tid = threadIdx.x;
    int bm = blockIdx.x, bn = blockIdx.y;
    int wid = tid >> 6, lane = tid & 63;
    int wm = wid * 16;                 // wave w: rows wm..wm+15 of the 64-row tile
    int l16 = lane & 15, q = lane >> 4;

    const ushort* Abase = xd64 + (size_t)bm * 64 * DT_RANK;
    const ushort* Bbase = dtwq + (size_t)bn * 64 * DT_RANK;
    #pragma unroll
    for (int i = tid; i < 512; i += 256) {
        int r = i >> 3, c = (i & 7) << 3;
        *(uint4*)(sA + r * 72 + c) = *(const uint4*)(Abase + (size_t)r * DT_RANK + c);
        *(uint4*)(sB + r * 72 + c) = *(const uint4*)(Bbase + (size_t)r * DT_RANK + c);
    }
    __syncthreads();

    f32x4 acc[4];
    #pragma unroll
    for (int j = 0; j < 4; j++) acc[j] = (f32x4){0.f, 0.f, 0.f, 0.f};

    #pragma unroll
    for (int ks = 0; ks < 2; ks++) {
        bf16x8 af = *(const bf16x8*)(sA + (wm + l16) * 72 + ks * 32 + q * 8);
        bf16x8 bfr[4];
        #pragma unroll
        for (int j = 0; j < 4; j++)
            bfr[j] = *(const bf16x8*)(sB + (j * 16 + l16) * 72 + ks * 32 + q * 8);
        #pragma unroll
        for (int j = 0; j < 4; j++)
            acc[j] = __builtin_amdgcn_mfma_f32_16x16x32_bf16(af, bfr[j], acc[j], 0, 0, 0);
    }

    // bias + softplus -> bf16 staged in LDS (reuse sA), then coalesced stores
    __syncthreads();
    #pragma unroll
    for (int j = 0; j < 4; j++) {
        float bias = dtb[bn * 64 + j * 16 + l16];
        #pragma unroll
        for (int r = 0; r < 4; r++) {
            float s = acc[j][r] + bias;
            float sp = (s > 20.f) ? s : log1pf(__expf(s));
            sA[(wm + q * 4 + r) * 72 + j * 16 + l16] = f2b(sp);
        }
    }
    __syncthreads();
    int row0 = bm * 64, col0 = bn * 64;
    #pragma unroll
    for (int rep = 0; rep < 2; rep++) {
        int off = rep * 2048 + tid * 8;
        int row = off >> 6, col = off & 63;
        *(uint4*)(dtout + (size_t)(row0 + row) * D_INNER + col0 + col) =
            *(const uint4*)(sA + row * 72 + col);
    }
}

// ---------- K5a: scan pass A — per-chunk (aprod, h_local) ----------
__global__ __launch_bounds__(256) void scan_partA_kernel(
    const ushort* __restrict__ dt, const float* __restrict__ xc,
    const float* __restrict__ xdbl, const float* __restrict__ Alog,
    float2* __restrict__ chunkAH)
{
    int bid = blockIdx.x;
    int c  = bid & (NCH - 1);
    int dg = (bid >> 3) & 127;
    int b  = bid >> 10;
    int tid = threadIdx.x;
    int n = tid & 15;
    int d = dg * 16 + (tid >> 4);

    float A = -__expf(Alog[d * D_STATE + n]);
    int l0 = c * LC;
    const ushort* dtp = dt + ((size_t)(b * LSEQ + l0)) * D_INNER + d;
    const float* xcp = xc + ((size_t)(b * LSEQ + l0)) * D_INNER + d;
    const float* Bp  = xdbl + ((size_t)(b * LSEQ + l0)) * 96 + 64 + n;

    float aprod = 1.f, hl = 0.f;
    #pragma unroll 4
    for (int l = 0; l < LC; l++) {
        float dtv = b2f(dtp[l * D_INNER]);
        float xcv = xcp[l * D_INNER];
        float Bv  = Bp[l * 96];
        float a = __expf(dtv * A);
        hl = a * hl + dtv * xcv * Bv;
        aprod *= a;
    }
    size_t idx = ((size_t)((b * D_INNER + d) * D_STATE + n)) * NCH + c;
    chunkAH[idx] = (float2){aprod, hl};
}

// ---------- K5b: stitch ----------
__global__ __launch_bounds__(256) void scan_partB_kernel(
    const float2* __restrict__ chunkAH, float* __restrict__ hinit)
{
    int kk = blockIdx.x * 256 + threadIdx.x;   // 65536 recurrences
    const float2* p = chunkAH + (size_t)kk * NCH;
    float* q = hinit + (size_t)kk * NCH;
    float run = 0.f;
    #pragma unroll
    for (int c = 0; c < NCH; c++) {
        q[c] = run;
        float2 v = p[c];
        run = v.x * run + v.y;
    }
}

// ---------- K5c: scan pass C — recompute with h_init, project, gate ----------
__global__ __launch_bounds__(256) void scan_partC_kernel(
    const ushort* __restrict__ dt, const float* __restrict__ xc,
    const float* __restrict__ xdbl, const float* __restrict__ xz,
    const float* __restrict__ Alog, const float* __restrict__ Dp,
    const float* __restrict__ hinit, ushort* __restrict__ yg)
{
    int bid = blockIdx.x;
    int c  = bid & (NCH - 1);
    int dg = (bid >> 3) & 127;
    int b  = bid >> 10;
    int tid = threadIdx.x;
    int n = tid & 15;
    int d = dg * 16 + (tid >> 4);

    float A = -__expf(Alog[d * D_STATE + n]);
    float Dd = Dp[d];
    int l0 = c * LC;
    const ushort* dtp = dt + ((size_t)(b * LSEQ + l0)) * D_INNER + d;
    const float* xcp = xc + ((size_t)(b * LSEQ + l0)) * D_INNER + d;
    const float* Bp  = xdbl + ((size_t)(b * LSEQ + l0)) * 96 + 64 + n;
    const float* Cp  = Bp + 16;
    const float* zp  = xz + ((size_t)(b * LSEQ + l0)) * (2 * D_INNER) + D_INNER + d;
    ushort* yp = yg + ((size_t)(b * LSEQ + l0)) * D_INNER + d;

    float h = hinit[((size_t)((b * D_INNER + d) * D_STATE + n)) * NCH + c];

    #pragma unroll 4
    for (int l = 0; l < LC; l++) {
        float dtv = b2f(dtp[l * D_INNER]);
        float xcv = xcp[l * D_INNER];
        float Bv  = Bp[l * 96];
        float Cv  = Cp[l * 96];
        float a = __expf(dtv * A);
        h = a * h + dtv * xcv * Bv;
        float p = h * Cv;
        p += __shfl_xor(p, 1);
        p += __shfl_xor(p, 2);
        p += __shfl_xor(p, 4);
        p += __shfl_xor(p, 8);
        if (n == 0) {
            float zv = zp[l * (2 * D_INNER)];
            float y = p + Dd * xcv;
            float sz = zv / (1.f + __expf(-zv));
            yp[(size_t)l * D_INNER] = f2b(y * sz);
        }
    }
}

extern "C" void kernel_launch(void* const* d_in, const int* in_sizes, int n_in,
                              void* d_out, int out_size, void* d_ws, size_t ws_size,
                              hipStream_t stream)
{
    const float* hs      = (const float*)d_in[0];
    const float* norm_w  = (const float*)d_in[1];
    const float* inproj  = (const float*)d_in[2];
    const float* convw   = (const float*)d_in[3];
    const float* convb   = (const float*)d_in[4];
    const float* xprojw  = (const float*)d_in[5];
    const float* dtw     = (const float*)d_in[6];
    const float* dtb     = (const float*)d_in[7];
    const float* alog    = (const float*)d_in[8];
    const float* dvec    = (const float*)d_in[9];
    const float* outproj = (const float*)d_in[10];

    float* out_main  = (float*)d_out;                        // (B,L,D_MODEL) f32
    float* out_resid = (float*)d_out + (size_t)NTOK * D_MODEL;

    char* ws = (char*)d_ws;
    float*  xz_f32  = (float*)(ws);                          // 32MB
    float*  xc_f32  = (float*)(ws + 33554432);               // 16MB
    ushort* dt_bf16 = (ushort*)(ws + 50331648);              // 8MB (in old dt region)
    float*  xdbl    = (float*)(ws + 67108864);               // 768KB
    ushort* h_bf16  = (ushort*)(ws + 67895296);              // 4MB — dead after K2
    ushort* yg_bf16 = (ushort*)(ws + 72089600);              // 8MB — written K5c
    ushort* wIn     = (ushort*)(ws + 80478208);              // 8MB — dead after K2
    ushort* wOut    = (ushort*)(ws + 88866816);              // 4MB
    // overlays (lifetimes disjoint from hosts):
    ushort* xpw_b   = (ushort*)(ws + 67895296);              // 384KB in h_bf16 region
    ushort* dtw_b   = (ushort*)(ws + 68288512);              // 256KB
    ushort* xd64_b  = (ushort*)(ws + 68550656);              // 256KB
    ushort* xc_bf16 = (ushort*)(ws + 72089600);              // 8MB in yg region (dead before K5c)
    float2* chunkAH = (float2*)(ws + 80478208);              // 4MB in wIn region
    float*  hinit   = (float*)(ws + 84672512);               // 2MB

    // weight conversions for the big GEMMs
    cvt_bf16_kernel<<<(2 * D_INNER * D_MODEL / 4 + 255) / 256, 256, 0, stream>>>(
        inproj, wIn, 2 * D_INNER * D_MODEL / 4);
    cvt_bf16_kernel<<<(D_MODEL * D_INNER / 4 + 255) / 256, 256, 0, stream>>>(
        outproj, wOut, D_MODEL * D_INNER / 4);

    // K1: RMSNorm + residual copy
    rmsnorm_kernel<<<NTOK, 256, 0, stream>>>(hs, norm_w, h_bf16, out_resid);

    // K2: xz = h @ in_proj_w^T
    gemm_bt_kernel<<<dim3(NTOK / 128, (2 * D_INNER) / 128), 256, 0, stream>>>(
        h_bf16, wIn, xz_f32, NTOK, 2 * D_INNER, D_MODEL);

    // small weight conversions (into h_bf16 region — free after K2)
    cvt_bf16_kernel<<<(96 * D_INNER / 4 + 255) / 256, 256, 0, stream>>>(
        xprojw, xpw_b, 96 * D_INNER / 4);
    cvt_bf16_kernel<<<(D_INNER * DT_RANK / 4 + 255) / 256, 256, 0, stream>>>(
        dtw, dtw_b, D_INNER * DT_RANK / 4);

    // K3: conv + SiLU (f32 + bf16)
    conv_silu_kernel<<<(NTOK * D_INNER) / 256, 256, 0, stream>>>(
        xz_f32, convw, convb, xc_f32, xc_bf16);

    // K4a: x_dbl GEMM (MFMA)
    xproj_gemm_kernel<<<NTOK / 128, 256, 0, stream>>>(xc_bf16, xpw_b, xdbl, xd64_b);

    // K4b: dt GEMM (MFMA) + bias + softplus -> bf16, 1024 blocks
    dt_gemm_kernel<<<dim3(NTOK / 64, D_INNER / 64), 256, 0, stream>>>(
        xd64_b, dtw_b, dtb, dt_bf16);

    // K5: chunked parallel scan
    scan_partA_kernel<<<2048, 256, 0, stream>>>(dt_bf16, xc_f32, xdbl, alog, chunkAH);
    scan_partB_kernel<<<256, 256, 0, stream>>>(chunkAH, hinit);
    scan_partC_kernel<<<2048, 256, 0, stream>>>(dt_bf16, xc_f32, xdbl, xz_f32,
                                                alog, dvec, hinit, yg_bf16);

    // K6: out = yg @ out_proj_w^T
    gemm_bt_kernel<<<dim3(NTOK / 128, D_MODEL / 128), 256, 0, stream>>>(
        yg_bf16, wOut, out_main, NTOK, D_MODEL, D_INNER);
}

// Round 6
// 363.372 us; speedup vs baseline: 2.4005x; 1.1841x over previous
//
#include <hip/hip_runtime.h>

// ---------- common helpers ----------
typedef __bf16 bf16x8 __attribute__((ext_vector_type(8)));
typedef float f32x4 __attribute__((ext_vector_type(4)));

__device__ __forceinline__ float b2f(ushort u) {
    union { unsigned int i; float f; } v;
    v.i = ((unsigned int)u) << 16;
    return v.f;
}
__device__ __forceinline__ ushort f2b(float f) {
    union { float f; unsigned int i; } v;
    v.f = f;
    unsigned int x = v.i;
    unsigned int r = (x + 0x7fffu + ((x >> 16) & 1u)) >> 16;
    return (ushort)r;
}

#define D_MODEL 1024
#define D_INNER 2048
#define D_STATE 16
#define DT_RANK 64
#define NTOK    2048   // B*L
#define LSEQ    1024
#define NCH     32     // scan chunks
#define LC      32     // steps per chunk

// ---------- K0: f32 -> bf16 conversion ----------
__global__ __launch_bounds__(256) void cvt_bf16_kernel(
    const float* __restrict__ src, ushort* __restrict__ dst, int n4)
{
    int i = blockIdx.x * 256 + threadIdx.x;
    if (i >= n4) return;
    float4 v = *(const float4*)(src + i * 4);
    ushort4 o;
    o.x = f2b(v.x); o.y = f2b(v.y); o.z = f2b(v.z); o.w = f2b(v.w);
    *(ushort4*)(dst + i * 4) = o;
}

// ---------- K1: RMSNorm (f32 in, bf16 h out) + residual f32 copy ----------
__global__ __launch_bounds__(256) void rmsnorm_kernel(
    const float* __restrict__ hs, const float* __restrict__ w,
    ushort* __restrict__ hout, float* __restrict__ resid)
{
    int t = blockIdx.x;
    int tid = threadIdx.x;
    float4 r4 = *(const float4*)(hs + (size_t)t * D_MODEL + tid * 4);
    float s = r4.x * r4.x + r4.y * r4.y + r4.z * r4.z + r4.w * r4.w;
    #pragma unroll
    for (int off = 32; off >= 1; off >>= 1) s += __shfl_xor(s, off);
    __shared__ float red[4];
    int lane = tid & 63, wid = tid >> 6;
    if (lane == 0) red[wid] = s;
    __syncthreads();
    float tot = red[0] + red[1] + red[2] + red[3];
    float inv = 1.0f / (sqrtf(tot) * (1.0f / 32.0f) + 1e-5f);
    float4 w4 = *(const float4*)(w + tid * 4);
    ushort4 o;
    o.x = f2b(w4.x * r4.x * inv);
    o.y = f2b(w4.y * r4.y * inv);
    o.z = f2b(w4.z * r4.z * inv);
    o.w = f2b(w4.w * r4.w * inv);
    *(ushort4*)(hout + (size_t)t * D_MODEL + tid * 4) = o;
    *(float4*)(resid + (size_t)t * D_MODEL + tid * 4) = r4;   // exact copy
}

// ---------- MFMA GEMM: C(MxN) = A(MxK) @ W(NxK)^T, bf16 in, f32 out ----------
__global__ __launch_bounds__(256) void gemm_bt_kernel(
    const ushort* __restrict__ Ag, const ushort* __restrict__ Wg,
    float* __restrict__ Cf, int M, int N, int K)
{
    __shared__ __align__(16) ushort sA[128 * 32];
    __shared__ __align__(16) ushort sB[128 * 32];
    int tid = threadIdx.x;
    int bm = blockIdx.x, bn = blockIdx.y;
    int wid = tid >> 6, lane = tid & 63;
    int wm = (wid >> 1) * 64, wn = (wid & 1) * 64;
    int l16 = lane & 15, q = lane >> 4;

    f32x4 acc[4][4];
    #pragma unroll
    for (int i = 0; i < 4; i++)
        #pragma unroll
        for (int j = 0; j < 4; j++)
            acc[i][j] = (f32x4){0.f, 0.f, 0.f, 0.f};

    const ushort* Abase = Ag + (size_t)bm * 128 * K;
    const ushort* Wbase = Wg + (size_t)bn * 128 * K;

    for (int k0 = 0; k0 < K; k0 += 32) {
        __syncthreads();
        #pragma unroll
        for (int i = tid; i < 512; i += 256) {
            int r = i >> 2, c = (i & 3) << 3;
            *(uint4*)(sA + i * 8) = *(const uint4*)(Abase + (size_t)r * K + k0 + c);
            *(uint4*)(sB + i * 8) = *(const uint4*)(Wbase + (size_t)r * K + k0 + c);
        }
        __syncthreads();
        bf16x8 af[4], bfr[4];
        #pragma unroll
        for (int i = 0; i < 4; i++)
            af[i] = *(const bf16x8*)(sA + (wm + i * 16 + l16) * 32 + q * 8);
        #pragma unroll
        for (int j = 0; j < 4; j++)
            bfr[j] = *(const bf16x8*)(sB + (wn + j * 16 + l16) * 32 + q * 8);
        #pragma unroll
        for (int i = 0; i < 4; i++)
            #pragma unroll
            for (int j = 0; j < 4; j++)
                acc[i][j] = __builtin_amdgcn_mfma_f32_16x16x32_bf16(af[i], bfr[j], acc[i][j], 0, 0, 0);
    }

    int row0 = bm * 128 + wm + q * 4;
    int col0 = bn * 128 + wn + l16;
    #pragma unroll
    for (int i = 0; i < 4; i++)
        #pragma unroll
        for (int j = 0; j < 4; j++)
            #pragma unroll
            for (int r = 0; r < 4; r++)
                Cf[(size_t)(row0 + i * 16 + r) * N + col0 + j * 16] = acc[i][j][r];
}

// ---------- K3: causal depthwise conv (4 taps) + SiLU (f32 + bf16 out) ----------
__global__ __launch_bounds__(256) void conv_silu_kernel(
    const float* __restrict__ xz, const float* __restrict__ cw,
    const float* __restrict__ cb, float* __restrict__ xc, ushort* __restrict__ xcb)
{
    int idx = blockIdx.x * 256 + threadIdx.x;     // (token, d) flat over 4M
    int d = idx & (D_INNER - 1);
    int t = idx >> 11;
    int l = t & (LSEQ - 1), b = t >> 10;
    float4 w4 = *(const float4*)(cw + d * 4);
    float acc = cb[d];
    float wk[4] = {w4.x, w4.y, w4.z, w4.w};
    #pragma unroll
    for (int k = 0; k < 4; k++) {
        int ll = l - 3 + k;
        float xv = (ll >= 0) ? xz[(((size_t)(b * LSEQ + ll)) << 12) + d] : 0.f;
        acc += xv * wk[k];
    }
    float sg = acc / (1.f + __expf(-acc));
    xc[idx] = sg;
    xcb[idx] = f2b(sg);
}

// ---------- K4a: x_dbl(2048x96) = xc_bf16 @ x_proj_w^T via MFMA ----------
__global__ __launch_bounds__(256) void xproj_gemm_kernel(
    const ushort* __restrict__ xcb, const ushort* __restrict__ wq,
    float* __restrict__ xdbl, ushort* __restrict__ xdbl64)
{
    __shared__ __align__(16) ushort sA[128 * 32];
    __shared__ __align__(16) ushort sB[96 * 32];
    int tid = threadIdx.x;
    int bm = blockIdx.x;
    int wid = tid >> 6, lane = tid & 63;
    int wm = wid * 32;
    int l16 = lane & 15, q = lane >> 4;

    f32x4 acc[2][6];
    #pragma unroll
    for (int i = 0; i < 2; i++)
        #pragma unroll
        for (int j = 0; j < 6; j++)
            acc[i][j] = (f32x4){0.f, 0.f, 0.f, 0.f};

    const ushort* Abase = xcb + (size_t)bm * 128 * D_INNER;

    for (int k0 = 0; k0 < D_INNER; k0 += 32) {
        __syncthreads();
        #pragma unroll
        for (int i = tid; i < 512; i += 256) {
            int r = i >> 2, c = (i & 3) << 3;
            *(uint4*)(sA + i * 8) = *(const uint4*)(Abase + (size_t)r * D_INNER + k0 + c);
        }
        for (int i = tid; i < 384; i += 256) {
            int r = i >> 2, c = (i & 3) << 3;
            *(uint4*)(sB + i * 8) = *(const uint4*)(wq + (size_t)r * D_INNER + k0 + c);
        }
        __syncthreads();
        bf16x8 af[2], bfr[6];
        #pragma unroll
        for (int i = 0; i < 2; i++)
            af[i] = *(const bf16x8*)(sA + (wm + i * 16 + l16) * 32 + q * 8);
        #pragma unroll
        for (int j = 0; j < 6; j++)
            bfr[j] = *(const bf16x8*)(sB + (j * 16 + l16) * 32 + q * 8);
        #pragma unroll
        for (int i = 0; i < 2; i++)
            #pragma unroll
            for (int j = 0; j < 6; j++)
                acc[i][j] = __builtin_amdgcn_mfma_f32_16x16x32_bf16(af[i], bfr[j], acc[i][j], 0, 0, 0);
    }

    int row0 = bm * 128 + wm + q * 4;
    #pragma unroll
    for (int i = 0; i < 2; i++)
        #pragma unroll
        for (int j = 0; j < 6; j++)
            #pragma unroll
            for (int r = 0; r < 4; r++) {
                int row = row0 + i * 16 + r;
                int col = j * 16 + l16;
                float v = acc[i][j][r];
                xdbl[(size_t)row * 96 + col] = v;
                if (col < DT_RANK) xdbl64[(size_t)row * DT_RANK + col] = f2b(v);
            }
}

// ---------- K4b: dt = softplus(xdbl64 @ dt_proj_w^T + b) -> bf16, coalesced ----------
__global__ __launch_bounds__(256) void dt_gemm_kernel(
    const ushort* __restrict__ xd64, const ushort* __restrict__ dtwq,
    const float* __restrict__ dtb, ushort* __restrict__ dtout)
{
    __shared__ __align__(16) ushort sA[64 * 72];   // also reused as bf16 output stage
    __shared__ __align__(16) ushort sB[64 * 72];
    int tid = threadIdx.x;
    int bm = blockIdx.x, bn = blockIdx.y;
    int wid = tid >> 6, lane = tid & 63;
    int wm = wid * 16;
    int l16 = lane & 15, q = lane >> 4;

    const ushort* Abase = xd64 + (size_t)bm * 64 * DT_RANK;
    const ushort* Bbase = dtwq + (size_t)bn * 64 * DT_RANK;
    #pragma unroll
    for (int i = tid; i < 512; i += 256) {
        int r = i >> 3, c = (i & 7) << 3;
        *(uint4*)(sA + r * 72 + c) = *(const uint4*)(Abase + (size_t)r * DT_RANK + c);
        *(uint4*)(sB + r * 72 + c) = *(const uint4*)(Bbase + (size_t)r * DT_RANK + c);
    }
    __syncthreads();

    f32x4 acc[4];
    #pragma unroll
    for (int j = 0; j < 4; j++) acc[j] = (f32x4){0.f, 0.f, 0.f, 0.f};

    #pragma unroll
    for (int ks = 0; ks < 2; ks++) {
        bf16x8 af = *(const bf16x8*)(sA + (wm + l16) * 72 + ks * 32 + q * 8);
        bf16x8 bfr[4];
        #pragma unroll
        for (int j = 0; j < 4; j++)
            bfr[j] = *(const bf16x8*)(sB + (j * 16 + l16) * 72 + ks * 32 + q * 8);
        #pragma unroll
        for (int j = 0; j < 4; j++)
            acc[j] = __builtin_amdgcn_mfma_f32_16x16x32_bf16(af, bfr[j], acc[j], 0, 0, 0);
    }

    __syncthreads();
    #pragma unroll
    for (int j = 0; j < 4; j++) {
        float bias = dtb[bn * 64 + j * 16 + l16];
        #pragma unroll
        for (int r = 0; r < 4; r++) {
            float s = acc[j][r] + bias;
            float sp = (s > 20.f) ? s : log1pf(__expf(s));
            sA[(wm + q * 4 + r) * 72 + j * 16 + l16] = f2b(sp);
        }
    }
    __syncthreads();
    int row0 = bm * 64, col0 = bn * 64;
    #pragma unroll
    for (int rep = 0; rep < 2; rep++) {
        int off = rep * 2048 + tid * 8;
        int row = off >> 6, col = off & 63;
        *(uint4*)(dtout + (size_t)(row0 + row) * D_INNER + col0 + col) =
            *(const uint4*)(sA + row * 72 + col);
    }
}

// ---------- K5a: scan pass A — lane-owns-d, 16 n-states in registers ----------
// grid 512 = b(2) x chunk(32) x dgroup(8); block = 4 waves x 64 d
__global__ __launch_bounds__(256) void scan_partA_kernel(
    const ushort* __restrict__ dt, const float* __restrict__ xc,
    const float* __restrict__ xdbl, const float* __restrict__ Alog,
    float2* __restrict__ ch1, float2* __restrict__ ch2)
{
    __shared__ float sBC[LC][32];
    int bid = blockIdx.x;
    int g = bid & 7;
    int c = (bid >> 3) & (NCH - 1);
    int b = bid >> 8;
    int tid = threadIdx.x;
    int lane = tid & 63, wid = tid >> 6;
    int d = g * 256 + wid * 64 + lane;
    int l0 = c * LC;

    {   // stage B/C tile: rows l0..l0+31, cols 64..95 of xdbl
        int r = tid >> 3, c4 = (tid & 7) * 4;
        *(float4*)&sBC[r][c4] =
            *(const float4*)(xdbl + ((size_t)(b * LSEQ + l0 + r)) * 96 + 64 + c4);
    }
    float A[16];
    #pragma unroll
    for (int k = 0; k < 4; k++)
        *(float4*)&A[k * 4] = *(const float4*)(Alog + d * D_STATE + k * 4);
    #pragma unroll
    for (int n = 0; n < 16; n++) A[n] = -__expf(A[n]);
    __syncthreads();

    const ushort* dtp = dt + ((size_t)(b * LSEQ + l0)) * D_INNER + d;
    const float*  xcp = xc + ((size_t)(b * LSEQ + l0)) * D_INNER + d;

    float h[16], ap[16];
    #pragma unroll
    for (int n = 0; n < 16; n++) { h[n] = 0.f; ap[n] = 1.f; }

    for (int l = 0; l < LC; l++) {
        float dtv = b2f(dtp[(size_t)l * D_INNER]);
        float xcv = xcp[(size_t)l * D_INNER];
        float t = dtv * xcv;
        float Bv[16];
        #pragma unroll
        for (int k = 0; k < 4; k++)
            *(float4*)&Bv[k * 4] = *(const float4*)&sBC[l][k * 4];
        #pragma unroll
        for (int n = 0; n < 16; n++) {
            float a = __expf(dtv * A[n]);
            h[n] = h[n] * a + t * Bv[n];
            ap[n] *= a;
        }
    }

    float2* outp = (c < 16 ? ch1 : ch2) +
                   ((size_t)((b * 16 + (c & 15)) * D_INNER + d)) * D_STATE;
    #pragma unroll
    for (int n = 0; n < 16; n += 2) {
        float4 v = {ap[n], h[n], ap[n + 1], h[n + 1]};
        *(float4*)&outp[n] = v;
    }
}

// ---------- K5b: stitch (in-place: .x becomes h_init for that chunk) ----------
__global__ __launch_bounds__(256) void scan_partB_kernel(
    float2* __restrict__ ch1, float2* __restrict__ ch2)
{
    int kk = blockIdx.x * 256 + threadIdx.x;   // 65536 = b(2) x d(2048) x n(16)
    int b = kk >> 15, dn = kk & 32767;
    float run = 0.f;
    #pragma unroll
    for (int c = 0; c < NCH; c++) {
        float2* p = (c < 16 ? ch1 : ch2) +
                    (size_t)(b * 16 + (c & 15)) * 32768 + dn;
        float2 v = *p;
        p->x = run;                 // h_init entering chunk c
        run = v.x * run + v.y;
    }
}

// ---------- K5c: scan pass C — lane-owns-d, fused C-proj + D-skip + gate ----------
__global__ __launch_bounds__(256) void scan_partC_kernel(
    const ushort* __restrict__ dt, const float* __restrict__ xc,
    const float* __restrict__ xdbl, const float* __restrict__ xz,
    const float* __restrict__ Alog, const float* __restrict__ Dp,
    const float2* __restrict__ ch1, const float2* __restrict__ ch2,
    ushort* __restrict__ yg)
{
    __shared__ float sBC[LC][32];
    int bid = blockIdx.x;
    int g = bid & 7;
    int c = (bid >> 3) & (NCH - 1);
    int b = bid >> 8;
    int tid = threadIdx.x;
    int lane = tid & 63, wid = tid >> 6;
    int d = g * 256 + wid * 64 + lane;
    int l0 = c * LC;

    {
        int r = tid >> 3, c4 = (tid & 7) * 4;
        *(float4*)&sBC[r][c4] =
            *(const float4*)(xdbl + ((size_t)(b * LSEQ + l0 + r)) * 96 + 64 + c4);
    }
    float A[16];
    #pragma unroll
    for (int k = 0; k < 4; k++)
        *(float4*)&A[k * 4] = *(const float4*)(Alog + d * D_STATE + k * 4);
    #pragma unroll
    for (int n = 0; n < 16; n++) A[n] = -__expf(A[n]);
    float Dd = Dp[d];

    const float2* hip_ = (c < 16 ? ch1 : ch2) +
                         ((size_t)((b * 16 + (c & 15)) * D_INNER + d)) * D_STATE;
    float h[16];
    #pragma unroll
    for (int n = 0; n < 16; n += 2) {
        float4 v = *(const float4*)&hip_[n];
        h[n] = v.x; h[n + 1] = v.z;
    }
    __syncthreads();

    const ushort* dtp = dt + ((size_t)(b * LSEQ + l0)) * D_INNER + d;
    const float*  xcp = xc + ((size_t)(b * LSEQ + l0)) * D_INNER + d;
    const float*  zp  = xz + ((size_t)(b * LSEQ + l0)) * (2 * D_INNER) + D_INNER + d;
    ushort* yp = yg + ((size_t)(b * LSEQ + l0)) * D_INNER + d;

    for (int l = 0; l < LC; l++) {
        float dtv = b2f(dtp[(size_t)l * D_INNER]);
        float xcv = xcp[(size_t)l * D_INNER];
        float zv  = zp[(size_t)l * (2 * D_INNER)];
        float t = dtv * xcv;
        float Bv[16], Cv[16];
        #pragma unroll
        for (int k = 0; k < 4; k++) {
            *(float4*)&Bv[k * 4] = *(const float4*)&sBC[l][k * 4];
            *(float4*)&Cv[k * 4] = *(const float4*)&sBC[l][16 + k * 4];
        }
        float p0 = 0.f, p1 = 0.f, p2 = 0.f, p3 = 0.f;
        #pragma unroll
        for (int n = 0; n < 16; n += 4) {
            float a0 = __expf(dtv * A[n]);
            float a1 = __expf(dtv * A[n + 1]);
            float a2 = __expf(dtv * A[n + 2]);
            float a3 = __expf(dtv * A[n + 3]);
            h[n]     = h[n] * a0 + t * Bv[n];
            h[n + 1] = h[n + 1] * a1 + t * Bv[n + 1];
            h[n + 2] = h[n + 2] * a2 + t * Bv[n + 2];
            h[n + 3] = h[n + 3] * a3 + t * Bv[n + 3];
            p0 += h[n] * Cv[n];
            p1 += h[n + 1] * Cv[n + 1];
            p2 += h[n + 2] * Cv[n + 2];
            p3 += h[n + 3] * Cv[n + 3];
        }
        float p = (p0 + p1) + (p2 + p3);
        float y = p + Dd * xcv;
        float sz = zv / (1.f + __expf(-zv));
        yp[(size_t)l * D_INNER] = f2b(y * sz);
    }
}

extern "C" void kernel_launch(void* const* d_in, const int* in_sizes, int n_in,
                              void* d_out, int out_size, void* d_ws, size_t ws_size,
                              hipStream_t stream)
{
    const float* hs      = (const float*)d_in[0];
    const float* norm_w  = (const float*)d_in[1];
    const float* inproj  = (const float*)d_in[2];
    const float* convw   = (const float*)d_in[3];
    const float* convb   = (const float*)d_in[4];
    const float* xprojw  = (const float*)d_in[5];
    const float* dtw     = (const float*)d_in[6];
    const float* dtb     = (const float*)d_in[7];
    const float* alog    = (const float*)d_in[8];
    const float* dvec    = (const float*)d_in[9];
    const float* outproj = (const float*)d_in[10];

    float* out_main  = (float*)d_out;                        // (B,L,D_MODEL) f32
    float* out_resid = (float*)d_out + (size_t)NTOK * D_MODEL;

    char* ws = (char*)d_ws;
    float*  xz_f32  = (float*)(ws);                          // 32MB
    float*  xc_f32  = (float*)(ws + 33554432);               // 16MB
    ushort* dt_bf16 = (ushort*)(ws + 50331648);              // 8MB
    float2* ch1     = (float2*)(ws + 58720256);              // 8MB — chunks 0..15 (was dt f32 2nd half)
    float*  xdbl    = (float*)(ws + 67108864);               // 768KB
    ushort* h_bf16  = (ushort*)(ws + 67895296);              // 4MB — dead after K2
    ushort* yg_bf16 = (ushort*)(ws + 72089600);              // 8MB — written K5c
    float2* ch2     = (float2*)(ws + 80478208);              // 8MB — chunks 16..31 (was wIn, dead after K2)
    ushort* wIn     = (ushort*)(ws + 80478208);              // 8MB — dead after K2
    ushort* wOut    = (ushort*)(ws + 88866816);              // 4MB
    // overlays (lifetimes disjoint from hosts):
    ushort* xpw_b   = (ushort*)(ws + 67895296);              // 384KB in h_bf16 region
    ushort* dtw_b   = (ushort*)(ws + 68288512);              // 256KB
    ushort* xd64_b  = (ushort*)(ws + 68550656);              // 256KB
    ushort* xc_bf16 = (ushort*)(ws + 72089600);              // 8MB in yg region (dead before K5c)

    // weight conversions for the big GEMMs
    cvt_bf16_kernel<<<(2 * D_INNER * D_MODEL / 4 + 255) / 256, 256, 0, stream>>>(
        inproj, wIn, 2 * D_INNER * D_MODEL / 4);
    cvt_bf16_kernel<<<(D_MODEL * D_INNER / 4 + 255) / 256, 256, 0, stream>>>(
        outproj, wOut, D_MODEL * D_INNER / 4);

    // K1: RMSNorm + residual copy
    rmsnorm_kernel<<<NTOK, 256, 0, stream>>>(hs, norm_w, h_bf16, out_resid);

    // K2: xz = h @ in_proj_w^T
    gemm_bt_kernel<<<dim3(NTOK / 128, (2 * D_INNER) / 128), 256, 0, stream>>>(
        h_bf16, wIn, xz_f32, NTOK, 2 * D_INNER, D_MODEL);

    // small weight conversions (into h_bf16 region — free after K2)
    cvt_bf16_kernel<<<(96 * D_INNER / 4 + 255) / 256, 256, 0, stream>>>(
        xprojw, xpw_b, 96 * D_INNER / 4);
    cvt_bf16_kernel<<<(D_INNER * DT_RANK / 4 + 255) / 256, 256, 0, stream>>>(
        dtw, dtw_b, D_INNER * DT_RANK / 4);

    // K3: conv + SiLU (f32 + bf16)
    conv_silu_kernel<<<(NTOK * D_INNER) / 256, 256, 0, stream>>>(
        xz_f32, convw, convb, xc_f32, xc_bf16);

    // K4a: x_dbl GEMM (MFMA)
    xproj_gemm_kernel<<<NTOK / 128, 256, 0, stream>>>(xc_bf16, xpw_b, xdbl, xd64_b);

    // K4b: dt GEMM (MFMA) + bias + softplus -> bf16
    dt_gemm_kernel<<<dim3(NTOK / 64, D_INNER / 64), 256, 0, stream>>>(
        xd64_b, dtw_b, dtb, dt_bf16);

    // K5: chunked parallel scan, lane-owns-d (A: local, B: stitch, C: finalize+gate)
    scan_partA_kernel<<<512, 256, 0, stream>>>(dt_bf16, xc_f32, xdbl, alog, ch1, ch2);
    scan_partB_kernel<<<256, 256, 0, stream>>>(ch1, ch2);
    scan_partC_kernel<<<512, 256, 0, stream>>>(dt_bf16, xc_f32, xdbl, xz_f32,
                                               alog, dvec, ch1, ch2, yg_bf16);

    // K6: out = yg @ out_proj_w^T
    gemm_bt_kernel<<<dim3(NTOK / 128, D_MODEL / 128), 256, 0, stream>>>(
        yg_bf16, wOut, out_main, NTOK, D_MODEL, D_INNER);
}

// Round 7
// 303.554 us; speedup vs baseline: 2.8736x; 1.1971x over previous
//
#include <hip/hip_runtime.h>

// ---------- common helpers ----------
typedef __bf16 bf16x8 __attribute__((ext_vector_type(8)));
typedef float f32x4 __attribute__((ext_vector_type(4)));

__device__ __forceinline__ float b2f(ushort u) {
    union { unsigned int i; float f; } v;
    v.i = ((unsigned int)u) << 16;
    return v.f;
}
__device__ __forceinline__ ushort f2b(float f) {
    union { float f; unsigned int i; } v;
    v.f = f;
    unsigned int x = v.i;
    unsigned int r = (x + 0x7fffu + ((x >> 16) & 1u)) >> 16;
    return (ushort)r;
}

#define D_MODEL 1024
#define D_INNER 2048
#define D_STATE 16
#define DT_RANK 64
#define NTOK    2048   // B*L
#define LSEQ    1024
#define NCH     32     // scan chunks
#define LC      32     // steps per chunk
#define KSL     16     // xproj K-slices

// ---------- K0: f32 -> bf16 conversion ----------
__global__ __launch_bounds__(256) void cvt_bf16_kernel(
    const float* __restrict__ src, ushort* __restrict__ dst, int n4)
{
    int i = blockIdx.x * 256 + threadIdx.x;
    if (i >= n4) return;
    float4 v = *(const float4*)(src + i * 4);
    ushort4 o;
    o.x = f2b(v.x); o.y = f2b(v.y); o.z = f2b(v.z); o.w = f2b(v.w);
    *(ushort4*)(dst + i * 4) = o;
}

// ---------- K1: RMSNorm (f32 in, bf16 h out) + residual f32 copy ----------
__global__ __launch_bounds__(256) void rmsnorm_kernel(
    const float* __restrict__ hs, const float* __restrict__ w,
    ushort* __restrict__ hout, float* __restrict__ resid)
{
    int t = blockIdx.x;
    int tid = threadIdx.x;
    float4 r4 = *(const float4*)(hs + (size_t)t * D_MODEL + tid * 4);
    float s = r4.x * r4.x + r4.y * r4.y + r4.z * r4.z + r4.w * r4.w;
    #pragma unroll
    for (int off = 32; off >= 1; off >>= 1) s += __shfl_xor(s, off);
    __shared__ float red[4];
    int lane = tid & 63, wid = tid >> 6;
    if (lane == 0) red[wid] = s;
    __syncthreads();
    float tot = red[0] + red[1] + red[2] + red[3];
    float inv = 1.0f / (sqrtf(tot) * (1.0f / 32.0f) + 1e-5f);
    float4 w4 = *(const float4*)(w + tid * 4);
    ushort4 o;
    o.x = f2b(w4.x * r4.x * inv);
    o.y = f2b(w4.y * r4.y * inv);
    o.z = f2b(w4.z * r4.z * inv);
    o.w = f2b(w4.w * r4.w * inv);
    *(ushort4*)(hout + (size_t)t * D_MODEL + tid * 4) = o;
    *(float4*)(resid + (size_t)t * D_MODEL + tid * 4) = r4;   // exact copy
}

// ---------- MFMA GEMM: C(MxN) = A(MxK) @ W(NxK)^T, bf16 in, f32 out ----------
__global__ __launch_bounds__(256) void gemm_bt_kernel(
    const ushort* __restrict__ Ag, const ushort* __restrict__ Wg,
    float* __restrict__ Cf, int M, int N, int K)
{
    __shared__ __align__(16) ushort sA[128 * 32];
    __shared__ __align__(16) ushort sB[128 * 32];
    int tid = threadIdx.x;
    int bm = blockIdx.x, bn = blockIdx.y;
    int wid = tid >> 6, lane = tid & 63;
    int wm = (wid >> 1) * 64, wn = (wid & 1) * 64;
    int l16 = lane & 15, q = lane >> 4;

    f32x4 acc[4][4];
    #pragma unroll
    for (int i = 0; i < 4; i++)
        #pragma unroll
        for (int j = 0; j < 4; j++)
            acc[i][j] = (f32x4){0.f, 0.f, 0.f, 0.f};

    const ushort* Abase = Ag + (size_t)bm * 128 * K;
    const ushort* Wbase = Wg + (size_t)bn * 128 * K;

    for (int k0 = 0; k0 < K; k0 += 32) {
        __syncthreads();
        #pragma unroll
        for (int i = tid; i < 512; i += 256) {
            int r = i >> 2, c = (i & 3) << 3;
            *(uint4*)(sA + i * 8) = *(const uint4*)(Abase + (size_t)r * K + k0 + c);
            *(uint4*)(sB + i * 8) = *(const uint4*)(Wbase + (size_t)r * K + k0 + c);
        }
        __syncthreads();
        bf16x8 af[4], bfr[4];
        #pragma unroll
        for (int i = 0; i < 4; i++)
            af[i] = *(const bf16x8*)(sA + (wm + i * 16 + l16) * 32 + q * 8);
        #pragma unroll
        for (int j = 0; j < 4; j++)
            bfr[j] = *(const bf16x8*)(sB + (wn + j * 16 + l16) * 32 + q * 8);
        #pragma unroll
        for (int i = 0; i < 4; i++)
            #pragma unroll
            for (int j = 0; j < 4; j++)
                acc[i][j] = __builtin_amdgcn_mfma_f32_16x16x32_bf16(af[i], bfr[j], acc[i][j], 0, 0, 0);
    }

    int row0 = bm * 128 + wm + q * 4;
    int col0 = bn * 128 + wn + l16;
    #pragma unroll
    for (int i = 0; i < 4; i++)
        #pragma unroll
        for (int j = 0; j < 4; j++)
            #pragma unroll
            for (int r = 0; r < 4; r++)
                Cf[(size_t)(row0 + i * 16 + r) * N + col0 + j * 16] = acc[i][j][r];
}

// ---------- K3: causal depthwise conv (4 taps) + SiLU (f32 + bf16 out) ----------
__global__ __launch_bounds__(256) void conv_silu_kernel(
    const float* __restrict__ xz, const float* __restrict__ cw,
    const float* __restrict__ cb, float* __restrict__ xc, ushort* __restrict__ xcb)
{
    int idx = blockIdx.x * 256 + threadIdx.x;     // (token, d) flat over 4M
    int d = idx & (D_INNER - 1);
    int t = idx >> 11;
    int l = t & (LSEQ - 1), b = t >> 10;
    float4 w4 = *(const float4*)(cw + d * 4);
    float acc = cb[d];
    float wk[4] = {w4.x, w4.y, w4.z, w4.w};
    #pragma unroll
    for (int k = 0; k < 4; k++) {
        int ll = l - 3 + k;
        float xv = (ll >= 0) ? xz[(((size_t)(b * LSEQ + ll)) << 12) + d] : 0.f;
        acc += xv * wk[k];
    }
    float sg = acc / (1.f + __expf(-acc));
    xc[idx] = sg;
    xcb[idx] = f2b(sg);
}

// ---------- K4a-1: xproj split-K partial GEMM ----------
// grid (16 M-tiles, 16 K-slices); block 128 rows x 96 cols x 128 K
__global__ __launch_bounds__(256) void xproj_partial_kernel(
    const ushort* __restrict__ xcb, const ushort* __restrict__ wq,
    float* __restrict__ partials)
{
    __shared__ __align__(16) ushort sA[128 * 32];
    __shared__ __align__(16) ushort sB[96 * 32];
    int tid = threadIdx.x;
    int bm = blockIdx.x, sl = blockIdx.y;
    int wid = tid >> 6, lane = tid & 63;
    int wm = wid * 32;
    int l16 = lane & 15, q = lane >> 4;

    f32x4 acc[2][6];
    #pragma unroll
    for (int i = 0; i < 2; i++)
        #pragma unroll
        for (int j = 0; j < 6; j++)
            acc[i][j] = (f32x4){0.f, 0.f, 0.f, 0.f};

    const ushort* Abase = xcb + (size_t)bm * 128 * D_INNER;
    int kbase = sl * (D_INNER / KSL);

    for (int kk = 0; kk < D_INNER / KSL; kk += 32) {
        int k0 = kbase + kk;
        __syncthreads();
        #pragma unroll
        for (int i = tid; i < 512; i += 256) {
            int r = i >> 2, c = (i & 3) << 3;
            *(uint4*)(sA + i * 8) = *(const uint4*)(Abase + (size_t)r * D_INNER + k0 + c);
        }
        for (int i = tid; i < 384; i += 256) {
            int r = i >> 2, c = (i & 3) << 3;
            *(uint4*)(sB + i * 8) = *(const uint4*)(wq + (size_t)r * D_INNER + k0 + c);
        }
        __syncthreads();
        bf16x8 af[2], bfr[6];
        #pragma unroll
        for (int i = 0; i < 2; i++)
            af[i] = *(const bf16x8*)(sA + (wm + i * 16 + l16) * 32 + q * 8);
        #pragma unroll
        for (int j = 0; j < 6; j++)
            bfr[j] = *(const bf16x8*)(sB + (j * 16 + l16) * 32 + q * 8);
        #pragma unroll
        for (int i = 0; i < 2; i++)
            #pragma unroll
            for (int j = 0; j < 6; j++)
                acc[i][j] = __builtin_amdgcn_mfma_f32_16x16x32_bf16(af[i], bfr[j], acc[i][j], 0, 0, 0);
    }

    float* out = partials + (size_t)sl * NTOK * 96;
    int row0 = bm * 128 + wm + q * 4;
    #pragma unroll
    for (int i = 0; i < 2; i++)
        #pragma unroll
        for (int j = 0; j < 6; j++)
            #pragma unroll
            for (int r = 0; r < 4; r++)
                out[(size_t)(row0 + i * 16 + r) * 96 + j * 16 + l16] = acc[i][j][r];
}

// ---------- K4a-2: xproj reduce (sum 16 partials) ----------
__global__ __launch_bounds__(256) void xproj_reduce_kernel(
    const float* __restrict__ partials, float* __restrict__ xdbl,
    ushort* __restrict__ xdbl64)
{
    int idx = blockIdx.x * 256 + threadIdx.x;    // 196608 outputs
    float s = 0.f;
    #pragma unroll
    for (int sl = 0; sl < KSL; sl++)
        s += partials[(size_t)sl * NTOK * 96 + idx];
    xdbl[idx] = s;
    int col = idx % 96;
    if (col < DT_RANK)
        xdbl64[(size_t)(idx / 96) * DT_RANK + col] = f2b(s);
}

// ---------- K4b: dt = softplus(xdbl64 @ dt_proj_w^T + b) -> bf16, coalesced ----------
__global__ __launch_bounds__(256) void dt_gemm_kernel(
    const ushort* __restrict__ xd64, const ushort* __restrict__ dtwq,
    const float* __restrict__ dtb, ushort* __restrict__ dtout)
{
    __shared__ __align__(16) ushort sA[64 * 72];   // also reused as bf16 output stage
    __shared__ __align__(16) ushort sB[64 * 72];
    int tid = threadIdx.x;
    int bm = blockIdx.x, bn = blockIdx.y;
    int wid = tid >> 6, lane = tid & 63;
    int wm = wid * 16;
    int l16 = lane & 15, q = lane >> 4;

    const ushort* Abase = xd64 + (size_t)bm * 64 * DT_RANK;
    const ushort* Bbase = dtwq + (size_t)bn * 64 * DT_RANK;
    #pragma unroll
    for (int i = tid; i < 512; i += 256) {
        int r = i >> 3, c = (i & 7) << 3;
        *(uint4*)(sA + r * 72 + c) = *(const uint4*)(Abase + (size_t)r * DT_RANK + c);
        *(uint4*)(sB + r * 72 + c) = *(const uint4*)(Bbase + (size_t)r * DT_RANK + c);
    }
    __syncthreads();

    f32x4 acc[4];
    #pragma unroll
    for (int j = 0; j < 4; j++) acc[j] = (f32x4){0.f, 0.f, 0.f, 0.f};

    #pragma unroll
    for (int ks = 0; ks < 2; ks++) {
        bf16x8 af = *(const bf16x8*)(sA + (wm + l16) * 72 + ks * 32 + q * 8);
        bf16x8 bfr[4];
        #pragma unroll
        for (int j = 0; j < 4; j++)
            bfr[j] = *(const bf16x8*)(sB + (j * 16 + l16) * 72 + ks * 32 + q * 8);
        #pragma unroll
        for (int j = 0; j < 4; j++)
            acc[j] = __builtin_amdgcn_mfma_f32_16x16x32_bf16(af, bfr[j], acc[j], 0, 0, 0);
    }

    __syncthreads();
    #pragma unroll
    for (int j = 0; j < 4; j++) {
        float bias = dtb[bn * 64 + j * 16 + l16];
        #pragma unroll
        for (int r = 0; r < 4; r++) {
            float s = acc[j][r] + bias;
            float sp = (s > 20.f) ? s : log1pf(__expf(s));
            sA[(wm + q * 4 + r) * 72 + j * 16 + l16] = f2b(sp);
        }
    }
    __syncthreads();
    int row0 = bm * 64, col0 = bn * 64;
    #pragma unroll
    for (int rep = 0; rep < 2; rep++) {
        int off = rep * 2048 + tid * 8;
        int row = off >> 6, col = off & 63;
        *(uint4*)(dtout + (size_t)(row0 + row) * D_INNER + col0 + col) =
            *(const uint4*)(sA + row * 72 + col);
    }
}

// ---------- K5a: scan pass A — lane-owns-d, 16 n-states in registers ----------
__global__ __launch_bounds__(256) void scan_partA_kernel(
    const ushort* __restrict__ dt, const float* __restrict__ xc,
    const float* __restrict__ xdbl, const float* __restrict__ Alog,
    float2* __restrict__ ch1, float2* __restrict__ ch2)
{
    __shared__ float sBC[LC][32];
    int bid = blockIdx.x;
    int g = bid & 7;
    int c = (bid >> 3) & (NCH - 1);
    int b = bid >> 8;
    int tid = threadIdx.x;
    int lane = tid & 63, wid = tid >> 6;
    int d = g * 256 + wid * 64 + lane;
    int l0 = c * LC;

    {   // stage B/C tile
        int r = tid >> 3, c4 = (tid & 7) * 4;
        *(float4*)&sBC[r][c4] =
            *(const float4*)(xdbl + ((size_t)(b * LSEQ + l0 + r)) * 96 + 64 + c4);
    }
    float A[16];
    #pragma unroll
    for (int k = 0; k < 4; k++)
        *(float4*)&A[k * 4] = *(const float4*)(Alog + d * D_STATE + k * 4);
    #pragma unroll
    for (int n = 0; n < 16; n++) A[n] = -__expf(A[n]);
    __syncthreads();

    const ushort* dtp = dt + ((size_t)(b * LSEQ + l0)) * D_INNER + d;
    const float*  xcp = xc + ((size_t)(b * LSEQ + l0)) * D_INNER + d;

    float h[16], ap[16];
    #pragma unroll
    for (int n = 0; n < 16; n++) { h[n] = 0.f; ap[n] = 1.f; }

    for (int l = 0; l < LC; l++) {
        float dtv = b2f(dtp[(size_t)l * D_INNER]);
        float xcv = xcp[(size_t)l * D_INNER];
        float t = dtv * xcv;
        float Bv[16];
        #pragma unroll
        for (int k = 0; k < 4; k++)
            *(float4*)&Bv[k * 4] = *(const float4*)&sBC[l][k * 4];
        #pragma unroll
        for (int n = 0; n < 16; n++) {
            float a = __expf(dtv * A[n]);
            h[n] = h[n] * a + t * Bv[n];
            ap[n] *= a;
        }
    }

    float2* outp = (c < 16 ? ch1 : ch2) +
                   ((size_t)((b * 16 + (c & 15)) * D_INNER + d)) * D_STATE;
    #pragma unroll
    for (int n = 0; n < 16; n += 2) {
        float4 v = {ap[n], h[n], ap[n + 1], h[n + 1]};
        *(float4*)&outp[n] = v;
    }
}

// ---------- K5b: stitch (in-place: .x becomes h_init for that chunk) ----------
__global__ __launch_bounds__(256) void scan_partB_kernel(
    float2* __restrict__ ch1, float2* __restrict__ ch2)
{
    int kk = blockIdx.x * 256 + threadIdx.x;   // 65536 = b(2) x d(2048) x n(16)
    int b = kk >> 15, dn = kk & 32767;
    float run = 0.f;
    #pragma unroll
    for (int c = 0; c < NCH; c++) {
        float2* p = (c < 16 ? ch1 : ch2) +
                    (size_t)(b * 16 + (c & 15)) * 32768 + dn;
        float2 v = *p;
        p->x = run;                 // h_init entering chunk c
        run = v.x * run + v.y;
    }
}

// ---------- K5c: scan pass C — lane-owns-d, fused C-proj + D-skip + gate ----------
__global__ __launch_bounds__(256) void scan_partC_kernel(
    const ushort* __restrict__ dt, const float* __restrict__ xc,
    const float* __restrict__ xdbl, const float* __restrict__ xz,
    const float* __restrict__ Alog, const float* __restrict__ Dp,
    const float2* __restrict__ ch1, const float2* __restrict__ ch2,
    ushort* __restrict__ yg)
{
    __shared__ float sBC[LC][32];
    int bid = blockIdx.x;
    int g = bid & 7;
    int c = (bid >> 3) & (NCH - 1);
    int b = bid >> 8;
    int tid = threadIdx.x;
    int lane = tid & 63, wid = tid >> 6;
    int d = g * 256 + wid * 64 + lane;
    int l0 = c * LC;

    {
        int r = tid >> 3, c4 = (tid & 7) * 4;
        *(float4*)&sBC[r][c4] =
            *(const float4*)(xdbl + ((size_t)(b * LSEQ + l0 + r)) * 96 + 64 + c4);
    }
    float A[16];
    #pragma unroll
    for (int k = 0; k < 4; k++)
        *(float4*)&A[k * 4] = *(const float4*)(Alog + d * D_STATE + k * 4);
    #pragma unroll
    for (int n = 0; n < 16; n++) A[n] = -__expf(A[n]);
    float Dd = Dp[d];

    const float2* hip_ = (c < 16 ? ch1 : ch2) +
                         ((size_t)((b * 16 + (c & 15)) * D_INNER + d)) * D_STATE;
    float h[16];
    #pragma unroll
    for (int n = 0; n < 16; n += 2) {
        float4 v = *(const float4*)&hip_[n];
        h[n] = v.x; h[n + 1] = v.z;
    }
    __syncthreads();

    const ushort* dtp = dt + ((size_t)(b * LSEQ + l0)) * D_INNER + d;
    const float*  xcp = xc + ((size_t)(b * LSEQ + l0)) * D_INNER + d;
    const float*  zp  = xz + ((size_t)(b * LSEQ + l0)) * (2 * D_INNER) + D_INNER + d;
    ushort* yp = yg + ((size_t)(b * LSEQ + l0)) * D_INNER + d;

    for (int l = 0; l < LC; l++) {
        float dtv = b2f(dtp[(size_t)l * D_INNER]);
        float xcv = xcp[(size_t)l * D_INNER];
        float zv  = zp[(size_t)l * (2 * D_INNER)];
        float t = dtv * xcv;
        float Bv[16], Cv[16];
        #pragma unroll
        for (int k = 0; k < 4; k++) {
            *(float4*)&Bv[k * 4] = *(const float4*)&sBC[l][k * 4];
            *(float4*)&Cv[k * 4] = *(const float4*)&sBC[l][16 + k * 4];
        }
        float p0 = 0.f, p1 = 0.f, p2 = 0.f, p3 = 0.f;
        #pragma unroll
        for (int n = 0; n < 16; n += 4) {
            float a0 = __expf(dtv * A[n]);
            float a1 = __expf(dtv * A[n + 1]);
            float a2 = __expf(dtv * A[n + 2]);
            float a3 = __expf(dtv * A[n + 3]);
            h[n]     = h[n] * a0 + t * Bv[n];
            h[n + 1] = h[n + 1] * a1 + t * Bv[n + 1];
            h[n + 2] = h[n + 2] * a2 + t * Bv[n + 2];
            h[n + 3] = h[n + 3] * a3 + t * Bv[n + 3];
            p0 += h[n] * Cv[n];
            p1 += h[n + 1] * Cv[n + 1];
            p2 += h[n + 2] * Cv[n + 2];
            p3 += h[n + 3] * Cv[n + 3];
        }
        float p = (p0 + p1) + (p2 + p3);
        float y = p + Dd * xcv;
        float sz = zv / (1.f + __expf(-zv));
        yp[(size_t)l * D_INNER] = f2b(y * sz);
    }
}

extern "C" void kernel_launch(void* const* d_in, const int* in_sizes, int n_in,
                              void* d_out, int out_size, void* d_ws, size_t ws_size,
                              hipStream_t stream)
{
    const float* hs      = (const float*)d_in[0];
    const float* norm_w  = (const float*)d_in[1];
    const float* inproj  = (const float*)d_in[2];
    const float* convw   = (const float*)d_in[3];
    const float* convb   = (const float*)d_in[4];
    const float* xprojw  = (const float*)d_in[5];
    const float* dtw     = (const float*)d_in[6];
    const float* dtb     = (const float*)d_in[7];
    const float* alog    = (const float*)d_in[8];
    const float* dvec    = (const float*)d_in[9];
    const float* outproj = (const float*)d_in[10];

    float* out_main  = (float*)d_out;                        // (B,L,D_MODEL) f32
    float* out_resid = (float*)d_out + (size_t)NTOK * D_MODEL;

    char* ws = (char*)d_ws;
    float*  xz_f32  = (float*)(ws);                          // 32MB
    float*  xc_f32  = (float*)(ws + 33554432);               // 16MB
    ushort* dt_bf16 = (ushort*)(ws + 50331648);              // 8MB (written AFTER xproj reduce)
    float2* ch1     = (float2*)(ws + 58720256);              // 8MB (written by scan_partA)
    float*  xdbl    = (float*)(ws + 67108864);               // 768KB
    ushort* h_bf16  = (ushort*)(ws + 67895296);              // 4MB — dead after K2
    ushort* yg_bf16 = (ushort*)(ws + 72089600);              // 8MB — written K5c
    float2* ch2     = (float2*)(ws + 80478208);              // 8MB (was wIn, dead after K2)
    ushort* wIn     = (ushort*)(ws + 80478208);              // 8MB — dead after K2
    ushort* wOut    = (ushort*)(ws + 88866816);              // 4MB
    // overlays (lifetimes disjoint from hosts):
    ushort* xpw_b   = (ushort*)(ws + 67895296);              // 384KB in h_bf16 region
    ushort* dtw_b   = (ushort*)(ws + 68288512);              // 256KB
    ushort* xd64_b  = (ushort*)(ws + 68550656);              // 256KB
    ushort* xc_bf16 = (ushort*)(ws + 72089600);              // 8MB in yg region (dead before K5c)
    float*  xprojP  = (float*)(ws + 50331648);               // 12.6MB partials: lives only
                                                             // between xproj_partial & reduce
                                                             // (overlaps dt_bf16+ch1 — both
                                                             //  written later)

    // weight conversions for the big GEMMs
    cvt_bf16_kernel<<<(2 * D_INNER * D_MODEL / 4 + 255) / 256, 256, 0, stream>>>(
        inproj, wIn, 2 * D_INNER * D_MODEL / 4);
    cvt_bf16_kernel<<<(D_MODEL * D_INNER / 4 + 255) / 256, 256, 0, stream>>>(
        outproj, wOut, D_MODEL * D_INNER / 4);

    // K1: RMSNorm + residual copy
    rmsnorm_kernel<<<NTOK, 256, 0, stream>>>(hs, norm_w, h_bf16, out_resid);

    // K2: xz = h @ in_proj_w^T
    gemm_bt_kernel<<<dim3(NTOK / 128, (2 * D_INNER) / 128), 256, 0, stream>>>(
        h_bf16, wIn, xz_f32, NTOK, 2 * D_INNER, D_MODEL);

    // small weight conversions (into h_bf16 region — free after K2)
    cvt_bf16_kernel<<<(96 * D_INNER / 4 + 255) / 256, 256, 0, stream>>>(
        xprojw, xpw_b, 96 * D_INNER / 4);
    cvt_bf16_kernel<<<(D_INNER * DT_RANK / 4 + 255) / 256, 256, 0, stream>>>(
        dtw, dtw_b, D_INNER * DT_RANK / 4);

    // K3: conv + SiLU (f32 + bf16)
    conv_silu_kernel<<<(NTOK * D_INNER) / 256, 256, 0, stream>>>(
        xz_f32, convw, convb, xc_f32, xc_bf16);

    // K4a: x_dbl GEMM — split-K partials then reduce
    xproj_partial_kernel<<<dim3(NTOK / 128, KSL), 256, 0, stream>>>(
        xc_bf16, xpw_b, xprojP);
    xproj_reduce_kernel<<<NTOK * 96 / 256, 256, 0, stream>>>(xprojP, xdbl, xd64_b);

    // K4b: dt GEMM (MFMA) + bias + softplus -> bf16
    dt_gemm_kernel<<<dim3(NTOK / 64, D_INNER / 64), 256, 0, stream>>>(
        xd64_b, dtw_b, dtb, dt_bf16);

    // K5: chunked parallel scan, lane-owns-d
    scan_partA_kernel<<<512, 256, 0, stream>>>(dt_bf16, xc_f32, xdbl, alog, ch1, ch2);
    scan_partB_kernel<<<256, 256, 0, stream>>>(ch1, ch2);
    scan_partC_kernel<<<512, 256, 0, stream>>>(dt_bf16, xc_f32, xdbl, xz_f32,
                                               alog, dvec, ch1, ch2, yg_bf16);

    // K6: out = yg @ out_proj_w^T
    gemm_bt_kernel<<<dim3(NTOK / 128, D_MODEL / 128), 256, 0, stream>>>(
        yg_bf16, wOut, out_main, NTOK, D_MODEL, D_INNER);
}

// Round 8
// 268.608 us; speedup vs baseline: 3.2474x; 1.1301x over previous
//
#include <hip/hip_runtime.h>

// ---------- common helpers ----------
typedef __bf16 bf16x8 __attribute__((ext_vector_type(8)));
typedef float f32x4 __attribute__((ext_vector_type(4)));

__device__ __forceinline__ float b2f(ushort u) {
    union { unsigned int i; float f; } v;
    v.i = ((unsigned int)u) << 16;
    return v.f;
}
__device__ __forceinline__ ushort f2b(float f) {
    union { float f; unsigned int i; } v;
    v.f = f;
    unsigned int x = v.i;
    unsigned int r = (x + 0x7fffu + ((x >> 16) & 1u)) >> 16;
    return (ushort)r;
}

#define D_MODEL 1024
#define D_INNER 2048
#define D_STATE 16
#define DT_RANK 64
#define NTOK    2048   // B*L
#define LSEQ    1024
#define NCH     32     // scan chunks
#define LC      32     // steps per chunk
#define KSL     16     // xproj K-slices

// ---------- K0: f32 -> bf16 conversion ----------
__global__ __launch_bounds__(256) void cvt_bf16_kernel(
    const float* __restrict__ src, ushort* __restrict__ dst, int n4)
{
    int i = blockIdx.x * 256 + threadIdx.x;
    if (i >= n4) return;
    float4 v = *(const float4*)(src + i * 4);
    ushort4 o;
    o.x = f2b(v.x); o.y = f2b(v.y); o.z = f2b(v.z); o.w = f2b(v.w);
    *(ushort4*)(dst + i * 4) = o;
}

// ---------- K1: RMSNorm (f32 in, bf16 h out) + residual f32 copy ----------
__global__ __launch_bounds__(256) void rmsnorm_kernel(
    const float* __restrict__ hs, const float* __restrict__ w,
    ushort* __restrict__ hout, float* __restrict__ resid)
{
    int t = blockIdx.x;
    int tid = threadIdx.x;
    float4 r4 = *(const float4*)(hs + (size_t)t * D_MODEL + tid * 4);
    float s = r4.x * r4.x + r4.y * r4.y + r4.z * r4.z + r4.w * r4.w;
    #pragma unroll
    for (int off = 32; off >= 1; off >>= 1) s += __shfl_xor(s, off);
    __shared__ float red[4];
    int lane = tid & 63, wid = tid >> 6;
    if (lane == 0) red[wid] = s;
    __syncthreads();
    float tot = red[0] + red[1] + red[2] + red[3];
    float inv = 1.0f / (sqrtf(tot) * (1.0f / 32.0f) + 1e-5f);
    float4 w4 = *(const float4*)(w + tid * 4);
    ushort4 o;
    o.x = f2b(w4.x * r4.x * inv);
    o.y = f2b(w4.y * r4.y * inv);
    o.z = f2b(w4.z * r4.z * inv);
    o.w = f2b(w4.w * r4.w * inv);
    *(ushort4*)(hout + (size_t)t * D_MODEL + tid * 4) = o;
    *(float4*)(resid + (size_t)t * D_MODEL + tid * 4) = r4;   // exact copy
}

// ---------- K2: 128x128 MFMA GEMM, reg-prefetch pipelined, padded LDS ----------
__global__ __launch_bounds__(256) void gemm_bt_kernel(
    const ushort* __restrict__ Ag, const ushort* __restrict__ Wg,
    float* __restrict__ Cf, int M, int N, int K)
{
    __shared__ __align__(16) ushort sA[128 * 40];
    __shared__ __align__(16) ushort sB[128 * 40];
    int tid = threadIdx.x;
    int bm = blockIdx.x, bn = blockIdx.y;
    int wid = tid >> 6, lane = tid & 63;
    int wm = (wid >> 1) * 64, wn = (wid & 1) * 64;
    int l16 = lane & 15, q = lane >> 4;

    f32x4 acc[4][4];
    #pragma unroll
    for (int i = 0; i < 4; i++)
        #pragma unroll
        for (int j = 0; j < 4; j++)
            acc[i][j] = (f32x4){0.f, 0.f, 0.f, 0.f};

    const ushort* Abase = Ag + (size_t)bm * 128 * K;
    const ushort* Wbase = Wg + (size_t)bn * 128 * K;

    int r0 = tid >> 2, c0 = (tid & 3) << 3;           // rows 0..63 (+64), 8-ushort chunks
    const ushort* pA0 = Abase + (size_t)r0 * K + c0;
    const ushort* pA1 = Abase + (size_t)(r0 + 64) * K + c0;
    const ushort* pB0 = Wbase + (size_t)r0 * K + c0;
    const ushort* pB1 = Wbase + (size_t)(r0 + 64) * K + c0;

    uint4 pa0 = *(const uint4*)(pA0), pa1 = *(const uint4*)(pA1);
    uint4 pb0 = *(const uint4*)(pB0), pb1 = *(const uint4*)(pB1);

    for (int k0 = 0; k0 < K; k0 += 32) {
        *(uint4*)(sA + r0 * 40 + c0)        = pa0;
        *(uint4*)(sA + (r0 + 64) * 40 + c0) = pa1;
        *(uint4*)(sB + r0 * 40 + c0)        = pb0;
        *(uint4*)(sB + (r0 + 64) * 40 + c0) = pb1;
        __syncthreads();
        if (k0 + 32 < K) {                             // prefetch next K-tile to regs
            pa0 = *(const uint4*)(pA0 + k0 + 32);
            pa1 = *(const uint4*)(pA1 + k0 + 32);
            pb0 = *(const uint4*)(pB0 + k0 + 32);
            pb1 = *(const uint4*)(pB1 + k0 + 32);
        }
        bf16x8 af[4], bfr[4];
        #pragma unroll
        for (int i = 0; i < 4; i++)
            af[i] = *(const bf16x8*)(sA + (wm + i * 16 + l16) * 40 + q * 8);
        #pragma unroll
        for (int j = 0; j < 4; j++)
            bfr[j] = *(const bf16x8*)(sB + (wn + j * 16 + l16) * 40 + q * 8);
        #pragma unroll
        for (int i = 0; i < 4; i++)
            #pragma unroll
            for (int j = 0; j < 4; j++)
                acc[i][j] = __builtin_amdgcn_mfma_f32_16x16x32_bf16(af[i], bfr[j], acc[i][j], 0, 0, 0);
        __syncthreads();
    }

    int row0 = bm * 128 + wm + q * 4;
    int col0 = bn * 128 + wn + l16;
    #pragma unroll
    for (int i = 0; i < 4; i++)
        #pragma unroll
        for (int j = 0; j < 4; j++)
            #pragma unroll
            for (int r = 0; r < 4; r++)
                Cf[(size_t)(row0 + i * 16 + r) * N + col0 + j * 16] = acc[i][j][r];
}

// ---------- K6: 64x64 MFMA GEMM (high block count), pipelined, padded LDS ----------
__global__ __launch_bounds__(256) void gemm64_kernel(
    const ushort* __restrict__ Ag, const ushort* __restrict__ Wg,
    float* __restrict__ Cf, int M, int N, int K)
{
    __shared__ __align__(16) ushort sA[64 * 72];
    __shared__ __align__(16) ushort sB[64 * 72];
    int tid = threadIdx.x;
    int bm = blockIdx.x, bn = blockIdx.y;
    int wid = tid >> 6, lane = tid & 63;
    int wm = wid * 16;
    int l16 = lane & 15, q = lane >> 4;

    f32x4 acc[4];
    #pragma unroll
    for (int j = 0; j < 4; j++) acc[j] = (f32x4){0.f, 0.f, 0.f, 0.f};

    const ushort* Abase = Ag + (size_t)bm * 64 * K;
    const ushort* Wbase = Wg + (size_t)bn * 64 * K;

    int r0 = tid >> 3, c0 = (tid & 7) << 3;           // rows 0..31 (+32), BK=64
    const ushort* pA0 = Abase + (size_t)r0 * K + c0;
    const ushort* pA1 = Abase + (size_t)(r0 + 32) * K + c0;
    const ushort* pB0 = Wbase + (size_t)r0 * K + c0;
    const ushort* pB1 = Wbase + (size_t)(r0 + 32) * K + c0;

    uint4 pa0 = *(const uint4*)(pA0), pa1 = *(const uint4*)(pA1);
    uint4 pb0 = *(const uint4*)(pB0), pb1 = *(const uint4*)(pB1);

    for (int k0 = 0; k0 < K; k0 += 64) {
        *(uint4*)(sA + r0 * 72 + c0)        = pa0;
        *(uint4*)(sA + (r0 + 32) * 72 + c0) = pa1;
        *(uint4*)(sB + r0 * 72 + c0)        = pb0;
        *(uint4*)(sB + (r0 + 32) * 72 + c0) = pb1;
        __syncthreads();
        if (k0 + 64 < K) {
            pa0 = *(const uint4*)(pA0 + k0 + 64);
            pa1 = *(const uint4*)(pA1 + k0 + 64);
            pb0 = *(const uint4*)(pB0 + k0 + 64);
            pb1 = *(const uint4*)(pB1 + k0 + 64);
        }
        #pragma unroll
        for (int ks = 0; ks < 2; ks++) {
            bf16x8 af = *(const bf16x8*)(sA + (wm + l16) * 72 + ks * 32 + q * 8);
            bf16x8 bfr[4];
            #pragma unroll
            for (int j = 0; j < 4; j++)
                bfr[j] = *(const bf16x8*)(sB + (j * 16 + l16) * 72 + ks * 32 + q * 8);
            #pragma unroll
            for (int j = 0; j < 4; j++)
                acc[j] = __builtin_amdgcn_mfma_f32_16x16x32_bf16(af, bfr[j], acc[j], 0, 0, 0);
        }
        __syncthreads();
    }

    int row0 = bm * 64 + wm + q * 4;
    int col0 = bn * 64 + l16;
    #pragma unroll
    for (int j = 0; j < 4; j++)
        #pragma unroll
        for (int r = 0; r < 4; r++)
            Cf[(size_t)(row0 + r) * N + col0 + j * 16] = acc[j][r];
}

// ---------- K3: causal depthwise conv (4 taps) + SiLU (f32 + bf16 out) ----------
__global__ __launch_bounds__(256) void conv_silu_kernel(
    const float* __restrict__ xz, const float* __restrict__ cw,
    const float* __restrict__ cb, float* __restrict__ xc, ushort* __restrict__ xcb)
{
    int idx = blockIdx.x * 256 + threadIdx.x;     // (token, d) flat over 4M
    int d = idx & (D_INNER - 1);
    int t = idx >> 11;
    int l = t & (LSEQ - 1), b = t >> 10;
    float4 w4 = *(const float4*)(cw + d * 4);
    float acc = cb[d];
    float wk[4] = {w4.x, w4.y, w4.z, w4.w};
    #pragma unroll
    for (int k = 0; k < 4; k++) {
        int ll = l - 3 + k;
        float xv = (ll >= 0) ? xz[(((size_t)(b * LSEQ + ll)) << 12) + d] : 0.f;
        acc += xv * wk[k];
    }
    float sg = acc / (1.f + __expf(-acc));
    xc[idx] = sg;
    xcb[idx] = f2b(sg);
}

// ---------- K4a-1: xproj split-K partial GEMM ----------
__global__ __launch_bounds__(256) void xproj_partial_kernel(
    const ushort* __restrict__ xcb, const ushort* __restrict__ wq,
    float* __restrict__ partials)
{
    __shared__ __align__(16) ushort sA[128 * 32];
    __shared__ __align__(16) ushort sB[96 * 32];
    int tid = threadIdx.x;
    int bm = blockIdx.x, sl = blockIdx.y;
    int wid = tid >> 6, lane = tid & 63;
    int wm = wid * 32;
    int l16 = lane & 15, q = lane >> 4;

    f32x4 acc[2][6];
    #pragma unroll
    for (int i = 0; i < 2; i++)
        #pragma unroll
        for (int j = 0; j < 6; j++)
            acc[i][j] = (f32x4){0.f, 0.f, 0.f, 0.f};

    const ushort* Abase = xcb + (size_t)bm * 128 * D_INNER;
    int kbase = sl * (D_INNER / KSL);

    for (int kk = 0; kk < D_INNER / KSL; kk += 32) {
        int k0 = kbase + kk;
        __syncthreads();
        #pragma unroll
        for (int i = tid; i < 512; i += 256) {
            int r = i >> 2, c = (i & 3) << 3;
            *(uint4*)(sA + i * 8) = *(const uint4*)(Abase + (size_t)r * D_INNER + k0 + c);
        }
        for (int i = tid; i < 384; i += 256) {
            int r = i >> 2, c = (i & 3) << 3;
            *(uint4*)(sB + i * 8) = *(const uint4*)(wq + (size_t)r * D_INNER + k0 + c);
        }
        __syncthreads();
        bf16x8 af[2], bfr[6];
        #pragma unroll
        for (int i = 0; i < 2; i++)
            af[i] = *(const bf16x8*)(sA + (wm + i * 16 + l16) * 32 + q * 8);
        #pragma unroll
        for (int j = 0; j < 6; j++)
            bfr[j] = *(const bf16x8*)(sB + (j * 16 + l16) * 32 + q * 8);
        #pragma unroll
        for (int i = 0; i < 2; i++)
            #pragma unroll
            for (int j = 0; j < 6; j++)
                acc[i][j] = __builtin_amdgcn_mfma_f32_16x16x32_bf16(af[i], bfr[j], acc[i][j], 0, 0, 0);
    }

    float* out = partials + (size_t)sl * NTOK * 96;
    int row0 = bm * 128 + wm + q * 4;
    #pragma unroll
    for (int i = 0; i < 2; i++)
        #pragma unroll
        for (int j = 0; j < 6; j++)
            #pragma unroll
            for (int r = 0; r < 4; r++)
                out[(size_t)(row0 + i * 16 + r) * 96 + j * 16 + l16] = acc[i][j][r];
}

// ---------- K4a-2: xproj reduce (sum 16 partials) ----------
__global__ __launch_bounds__(256) void xproj_reduce_kernel(
    const float* __restrict__ partials, float* __restrict__ xdbl,
    ushort* __restrict__ xdbl64)
{
    int idx = blockIdx.x * 256 + threadIdx.x;    // 196608 outputs
    float s = 0.f;
    #pragma unroll
    for (int sl = 0; sl < KSL; sl++)
        s += partials[(size_t)sl * NTOK * 96 + idx];
    xdbl[idx] = s;
    int col = idx % 96;
    if (col < DT_RANK)
        xdbl64[(size_t)(idx / 96) * DT_RANK + col] = f2b(s);
}

// ---------- K4b: dt = softplus(xdbl64 @ dt_proj_w^T + b) -> bf16, coalesced ----------
__global__ __launch_bounds__(256) void dt_gemm_kernel(
    const ushort* __restrict__ xd64, const ushort* __restrict__ dtwq,
    const float* __restrict__ dtb, ushort* __restrict__ dtout)
{
    __shared__ __align__(16) ushort sA[64 * 72];   // also reused as bf16 output stage
    __shared__ __align__(16) ushort sB[64 * 72];
    int tid = threadIdx.x;
    int bm = blockIdx.x, bn = blockIdx.y;
    int wid = tid >> 6, lane = tid & 63;
    int wm = wid * 16;
    int l16 = lane & 15, q = lane >> 4;

    const ushort* Abase = xd64 + (size_t)bm * 64 * DT_RANK;
    const ushort* Bbase = dtwq + (size_t)bn * 64 * DT_RANK;
    #pragma unroll
    for (int i = tid; i < 512; i += 256) {
        int r = i >> 3, c = (i & 7) << 3;
        *(uint4*)(sA + r * 72 + c) = *(const uint4*)(Abase + (size_t)r * DT_RANK + c);
        *(uint4*)(sB + r * 72 + c) = *(const uint4*)(Bbase + (size_t)r * DT_RANK + c);
    }
    __syncthreads();

    f32x4 acc[4];
    #pragma unroll
    for (int j = 0; j < 4; j++) acc[j] = (f32x4){0.f, 0.f, 0.f, 0.f};

    #pragma unroll
    for (int ks = 0; ks < 2; ks++) {
        bf16x8 af = *(const bf16x8*)(sA + (wm + l16) * 72 + ks * 32 + q * 8);
        bf16x8 bfr[4];
        #pragma unroll
        for (int j = 0; j < 4; j++)
            bfr[j] = *(const bf16x8*)(sB + (j * 16 + l16) * 72 + ks * 32 + q * 8);
        #pragma unroll
        for (int j = 0; j < 4; j++)
            acc[j] = __builtin_amdgcn_mfma_f32_16x16x32_bf16(af, bfr[j], acc[j], 0, 0, 0);
    }

    __syncthreads();
    #pragma unroll
    for (int j = 0; j < 4; j++) {
        float bias = dtb[bn * 64 + j * 16 + l16];
        #pragma unroll
        for (int r = 0; r < 4; r++) {
            float s = acc[j][r] + bias;
            float sp = (s > 20.f) ? s : log1pf(__expf(s));
            sA[(wm + q * 4 + r) * 72 + j * 16 + l16] = f2b(sp);
        }
    }
    __syncthreads();
    int row0 = bm * 64, col0 = bn * 64;
    #pragma unroll
    for (int rep = 0; rep < 2; rep++) {
        int off = rep * 2048 + tid * 8;
        int row = off >> 6, col = off & 63;
        *(uint4*)(dtout + (size_t)(row0 + row) * D_INNER + col0 + col) =
            *(const uint4*)(sA + row * 72 + col);
    }
}

// ---------- K5a: scan pass A — lane-owns-d, 16 n-states in registers ----------
__global__ __launch_bounds__(256) void scan_partA_kernel(
    const ushort* __restrict__ dt, const float* __restrict__ xc,
    const float* __restrict__ xdbl, const float* __restrict__ Alog,
    float2* __restrict__ ch1, float2* __restrict__ ch2)
{
    __shared__ float sBC[LC][32];
    int bid = blockIdx.x;
    int g = bid & 7;
    int c = (bid >> 3) & (NCH - 1);
    int b = bid >> 8;
    int tid = threadIdx.x;
    int lane = tid & 63, wid = tid >> 6;
    int d = g * 256 + wid * 64 + lane;
    int l0 = c * LC;

    {   // stage B/C tile
        int r = tid >> 3, c4 = (tid & 7) * 4;
        *(float4*)&sBC[r][c4] =
            *(const float4*)(xdbl + ((size_t)(b * LSEQ + l0 + r)) * 96 + 64 + c4);
    }
    float A[16];
    #pragma unroll
    for (int k = 0; k < 4; k++)
        *(float4*)&A[k * 4] = *(const float4*)(Alog + d * D_STATE + k * 4);
    #pragma unroll
    for (int n = 0; n < 16; n++) A[n] = -__expf(A[n]);
    __syncthreads();

    const ushort* dtp = dt + ((size_t)(b * LSEQ + l0)) * D_INNER + d;
    const float*  xcp = xc + ((size_t)(b * LSEQ + l0)) * D_INNER + d;

    float h[16], ap[16];
    #pragma unroll
    for (int n = 0; n < 16; n++) { h[n] = 0.f; ap[n] = 1.f; }

    for (int l = 0; l < LC; l++) {
        float dtv = b2f(dtp[(size_t)l * D_INNER]);
        float xcv = xcp[(size_t)l * D_INNER];
        float t = dtv * xcv;
        float Bv[16];
        #pragma unroll
        for (int k = 0; k < 4; k++)
            *(float4*)&Bv[k * 4] = *(const float4*)&sBC[l][k * 4];
        #pragma unroll
        for (int n = 0; n < 16; n++) {
            float a = __expf(dtv * A[n]);
            h[n] = h[n] * a + t * Bv[n];
            ap[n] *= a;
        }
    }

    float2* outp = (c < 16 ? ch1 : ch2) +
                   ((size_t)((b * 16 + (c & 15)) * D_INNER + d)) * D_STATE;
    #pragma unroll
    for (int n = 0; n < 16; n += 2) {
        float4 v = {ap[n], h[n], ap[n + 1], h[n + 1]};
        *(float4*)&outp[n] = v;
    }
}

// ---------- K5b: stitch (in-place: .x becomes h_init for that chunk) ----------
__global__ __launch_bounds__(256) void scan_partB_kernel(
    float2* __restrict__ ch1, float2* __restrict__ ch2)
{
    int kk = blockIdx.x * 256 + threadIdx.x;   // 65536 = b(2) x d(2048) x n(16)
    int b = kk >> 15, dn = kk & 32767;
    float run = 0.f;
    #pragma unroll
    for (int c = 0; c < NCH; c++) {
        float2* p = (c < 16 ? ch1 : ch2) +
                    (size_t)(b * 16 + (c & 15)) * 32768 + dn;
        float2 v = *p;
        p->x = run;                 // h_init entering chunk c
        run = v.x * run + v.y;
    }
}

// ---------- K5c: scan pass C — lane-owns-d, fused C-proj + D-skip + gate ----------
__global__ __launch_bounds__(256) void scan_partC_kernel(
    const ushort* __restrict__ dt, const float* __restrict__ xc,
    const float* __restrict__ xdbl, const float* __restrict__ xz,
    const float* __restrict__ Alog, const float* __restrict__ Dp,
    const float2* __restrict__ ch1, const float2* __restrict__ ch2,
    ushort* __restrict__ yg)
{
    __shared__ float sBC[LC][32];
    int bid = blockIdx.x;
    int g = bid & 7;
    int c = (bid >> 3) & (NCH - 1);
    int b = bid >> 8;
    int tid = threadIdx.x;
    int lane = tid & 63, wid = tid >> 6;
    int d = g * 256 + wid * 64 + lane;
    int l0 = c * LC;

    {
        int r = tid >> 3, c4 = (tid & 7) * 4;
        *(float4*)&sBC[r][c4] =
            *(const float4*)(xdbl + ((size_t)(b * LSEQ + l0 + r)) * 96 + 64 + c4);
    }
    float A[16];
    #pragma unroll
    for (int k = 0; k < 4; k++)
        *(float4*)&A[k * 4] = *(const float4*)(Alog + d * D_STATE + k * 4);
    #pragma unroll
    for (int n = 0; n < 16; n++) A[n] = -__expf(A[n]);
    float Dd = Dp[d];

    const float2* hip_ = (c < 16 ? ch1 : ch2) +
                         ((size_t)((b * 16 + (c & 15)) * D_INNER + d)) * D_STATE;
    float h[16];
    #pragma unroll
    for (int n = 0; n < 16; n += 2) {
        float4 v = *(const float4*)&hip_[n];
        h[n] = v.x; h[n + 1] = v.z;
    }
    __syncthreads();

    const ushort* dtp = dt + ((size_t)(b * LSEQ + l0)) * D_INNER + d;
    const float*  xcp = xc + ((size_t)(b * LSEQ + l0)) * D_INNER + d;
    const float*  zp  = xz + ((size_t)(b * LSEQ + l0)) * (2 * D_INNER) + D_INNER + d;
    ushort* yp = yg + ((size_t)(b * LSEQ + l0)) * D_INNER + d;

    for (int l = 0; l < LC; l++) {
        float dtv = b2f(dtp[(size_t)l * D_INNER]);
        float xcv = xcp[(size_t)l * D_INNER];
        float zv  = zp[(size_t)l * (2 * D_INNER)];
        float t = dtv * xcv;
        float Bv[16], Cv[16];
        #pragma unroll
        for (int k = 0; k < 4; k++) {
            *(float4*)&Bv[k * 4] = *(const float4*)&sBC[l][k * 4];
            *(float4*)&Cv[k * 4] = *(const float4*)&sBC[l][16 + k * 4];
        }
        float p0 = 0.f, p1 = 0.f, p2 = 0.f, p3 = 0.f;
        #pragma unroll
        for (int n = 0; n < 16; n += 4) {
            float a0 = __expf(dtv * A[n]);
            float a1 = __expf(dtv * A[n + 1]);
            float a2 = __expf(dtv * A[n + 2]);
            float a3 = __expf(dtv * A[n + 3]);
            h[n]     = h[n] * a0 + t * Bv[n];
            h[n + 1] = h[n + 1] * a1 + t * Bv[n + 1];
            h[n + 2] = h[n + 2] * a2 + t * Bv[n + 2];
            h[n + 3] = h[n + 3] * a3 + t * Bv[n + 3];
            p0 += h[n] * Cv[n];
            p1 += h[n + 1] * Cv[n + 1];
            p2 += h[n + 2] * Cv[n + 2];
            p3 += h[n + 3] * Cv[n + 3];
        }
        float p = (p0 + p1) + (p2 + p3);
        float y = p + Dd * xcv;
        float sz = zv / (1.f + __expf(-zv));
        yp[(size_t)l * D_INNER] = f2b(y * sz);
    }
}

extern "C" void kernel_launch(void* const* d_in, const int* in_sizes, int n_in,
                              void* d_out, int out_size, void* d_ws, size_t ws_size,
                              hipStream_t stream)
{
    const float* hs      = (const float*)d_in[0];
    const float* norm_w  = (const float*)d_in[1];
    const float* inproj  = (const float*)d_in[2];
    const float* convw   = (const float*)d_in[3];
    const float* convb   = (const float*)d_in[4];
    const float* xprojw  = (const float*)d_in[5];
    const float* dtw     = (const float*)d_in[6];
    const float* dtb     = (const float*)d_in[7];
    const float* alog    = (const float*)d_in[8];
    const float* dvec    = (const float*)d_in[9];
    const float* outproj = (const float*)d_in[10];

    float* out_main  = (float*)d_out;                        // (B,L,D_MODEL) f32
    float* out_resid = (float*)d_out + (size_t)NTOK * D_MODEL;

    char* ws = (char*)d_ws;
    float*  xz_f32  = (float*)(ws);                          // 32MB
    float*  xc_f32  = (float*)(ws + 33554432);               // 16MB
    ushort* dt_bf16 = (ushort*)(ws + 50331648);              // 8MB (written AFTER xproj reduce)
    float2* ch1     = (float2*)(ws + 58720256);              // 8MB (written by scan_partA)
    float*  xdbl    = (float*)(ws + 67108864);               // 768KB
    ushort* h_bf16  = (ushort*)(ws + 67895296);              // 4MB — dead after K2
    ushort* yg_bf16 = (ushort*)(ws + 72089600);              // 8MB — written K5c
    float2* ch2     = (float2*)(ws + 80478208);              // 8MB (was wIn, dead after K2)
    ushort* wIn     = (ushort*)(ws + 80478208);              // 8MB — dead after K2
    ushort* wOut    = (ushort*)(ws + 88866816);              // 4MB
    // overlays (lifetimes disjoint from hosts):
    ushort* xpw_b   = (ushort*)(ws + 67895296);              // 384KB in h_bf16 region
    ushort* dtw_b   = (ushort*)(ws + 68288512);              // 256KB
    ushort* xd64_b  = (ushort*)(ws + 68550656);              // 256KB
    ushort* xc_bf16 = (ushort*)(ws + 72089600);              // 8MB in yg region (dead before K5c)
    float*  xprojP  = (float*)(ws + 50331648);               // 12.6MB partials (overlaps
                                                             // dt_bf16+ch1 — both written later)

    // weight conversions for the big GEMMs
    cvt_bf16_kernel<<<(2 * D_INNER * D_MODEL / 4 + 255) / 256, 256, 0, stream>>>(
        inproj, wIn, 2 * D_INNER * D_MODEL / 4);
    cvt_bf16_kernel<<<(D_MODEL * D_INNER / 4 + 255) / 256, 256, 0, stream>>>(
        outproj, wOut, D_MODEL * D_INNER / 4);

    // K1: RMSNorm + residual copy
    rmsnorm_kernel<<<NTOK, 256, 0, stream>>>(hs, norm_w, h_bf16, out_resid);

    // K2: xz = h @ in_proj_w^T  (512 blocks, pipelined)
    gemm_bt_kernel<<<dim3(NTOK / 128, (2 * D_INNER) / 128), 256, 0, stream>>>(
        h_bf16, wIn, xz_f32, NTOK, 2 * D_INNER, D_MODEL);

    // small weight conversions (into h_bf16 region — free after K2)
    cvt_bf16_kernel<<<(96 * D_INNER / 4 + 255) / 256, 256, 0, stream>>>(
        xprojw, xpw_b, 96 * D_INNER / 4);
    cvt_bf16_kernel<<<(D_INNER * DT_RANK / 4 + 255) / 256, 256, 0, stream>>>(
        dtw, dtw_b, D_INNER * DT_RANK / 4);

    // K3: conv + SiLU (f32 + bf16)
    conv_silu_kernel<<<(NTOK * D_INNER) / 256, 256, 0, stream>>>(
        xz_f32, convw, convb, xc_f32, xc_bf16);

    // K4a: x_dbl GEMM — split-K partials then reduce
    xproj_partial_kernel<<<dim3(NTOK / 128, KSL), 256, 0, stream>>>(
        xc_bf16, xpw_b, xprojP);
    xproj_reduce_kernel<<<NTOK * 96 / 256, 256, 0, stream>>>(xprojP, xdbl, xd64_b);

    // K4b: dt GEMM (MFMA) + bias + softplus -> bf16
    dt_gemm_kernel<<<dim3(NTOK / 64, D_INNER / 64), 256, 0, stream>>>(
        xd64_b, dtw_b, dtb, dt_bf16);

    // K5: chunked parallel scan, lane-owns-d
    scan_partA_kernel<<<512, 256, 0, stream>>>(dt_bf16, xc_f32, xdbl, alog, ch1, ch2);
    scan_partB_kernel<<<256, 256, 0, stream>>>(ch1, ch2);
    scan_partC_kernel<<<512, 256, 0, stream>>>(dt_bf16, xc_f32, xdbl, xz_f32,
                                               alog, dvec, ch1, ch2, yg_bf16);

    // K6: out = yg @ out_proj_w^T  (512 blocks, 64x64 tiles, pipelined)
    gemm64_kernel<<<dim3(NTOK / 64, D_MODEL / 64), 256, 0, stream>>>(
        yg_bf16, wOut, out_main, NTOK, D_MODEL, D_INNER);
}

// Round 9
// 265.074 us; speedup vs baseline: 3.2907x; 1.0133x over previous
//
#include <hip/hip_runtime.h>

// ---------- common helpers ----------
typedef __bf16 bf16x8 __attribute__((ext_vector_type(8)));
typedef float f32x4 __attribute__((ext_vector_type(4)));

__device__ __forceinline__ float b2f(ushort u) {
    union { unsigned int i; float f; } v;
    v.i = ((unsigned int)u) << 16;
    return v.f;
}
__device__ __forceinline__ ushort f2b(float f) {
    union { float f; unsigned int i; } v;
    v.f = f;
    unsigned int x = v.i;
    unsigned int r = (x + 0x7fffu + ((x >> 16) & 1u)) >> 16;
    return (ushort)r;
}

#define D_MODEL 1024
#define D_INNER 2048
#define D_STATE 16
#define DT_RANK 64
#define NTOK    2048   // B*L
#define LSEQ    1024
#define NCH     32     // scan chunks
#define LC      32     // steps per chunk
#define KSL     16     // xproj K-slices

// ---------- K0: all weight f32->bf16 conversions in one launch ----------
// quads: inproj 1048576 | outproj 524288 | xprojw 49152 | dtw 32768
__global__ __launch_bounds__(256) void cvt_all_kernel(
    const float* __restrict__ inproj, const float* __restrict__ outproj,
    const float* __restrict__ xprojw, const float* __restrict__ dtw,
    ushort* __restrict__ wIn, ushort* __restrict__ wOut,
    ushort* __restrict__ xpw, ushort* __restrict__ dtwb)
{
    int i = blockIdx.x * 256 + threadIdx.x;
    const float* src; ushort* dst; int off;
    if (i < 1048576)      { src = inproj;  dst = wIn;  off = i; }
    else if (i < 1572864) { src = outproj; dst = wOut; off = i - 1048576; }
    else if (i < 1622016) { src = xprojw;  dst = xpw;  off = i - 1572864; }
    else if (i < 1654784) { src = dtw;     dst = dtwb; off = i - 1622016; }
    else return;
    float4 v = *(const float4*)(src + (size_t)off * 4);
    ushort4 o;
    o.x = f2b(v.x); o.y = f2b(v.y); o.z = f2b(v.z); o.w = f2b(v.w);
    *(ushort4*)(dst + (size_t)off * 4) = o;
}

// ---------- K1: RMSNorm (f32 in, bf16 h out) + residual f32 copy ----------
__global__ __launch_bounds__(256) void rmsnorm_kernel(
    const float* __restrict__ hs, const float* __restrict__ w,
    ushort* __restrict__ hout, float* __restrict__ resid)
{
    int t = blockIdx.x;
    int tid = threadIdx.x;
    float4 r4 = *(const float4*)(hs + (size_t)t * D_MODEL + tid * 4);
    float s = r4.x * r4.x + r4.y * r4.y + r4.z * r4.z + r4.w * r4.w;
    #pragma unroll
    for (int off = 32; off >= 1; off >>= 1) s += __shfl_xor(s, off);
    __shared__ float red[4];
    int lane = tid & 63, wid = tid >> 6;
    if (lane == 0) red[wid] = s;
    __syncthreads();
    float tot = red[0] + red[1] + red[2] + red[3];
    float inv = 1.0f / (sqrtf(tot) * (1.0f / 32.0f) + 1e-5f);
    float4 w4 = *(const float4*)(w + tid * 4);
    ushort4 o;
    o.x = f2b(w4.x * r4.x * inv);
    o.y = f2b(w4.y * r4.y * inv);
    o.z = f2b(w4.z * r4.z * inv);
    o.w = f2b(w4.w * r4.w * inv);
    *(ushort4*)(hout + (size_t)t * D_MODEL + tid * 4) = o;
    *(float4*)(resid + (size_t)t * D_MODEL + tid * 4) = r4;   // exact copy
}

// ---------- K2: xz GEMM 128x128, pipelined, bf16 out split into x/z halves ----------
__global__ __launch_bounds__(256) void gemm_xz_kernel(
    const ushort* __restrict__ Ag, const ushort* __restrict__ Wg,
    ushort* __restrict__ xq, ushort* __restrict__ zq, int K)
{
    __shared__ __align__(16) ushort sA[128 * 40];
    __shared__ __align__(16) ushort sB[128 * 40];
    int tid = threadIdx.x;
    int bm = blockIdx.x, bn = blockIdx.y;
    int wid = tid >> 6, lane = tid & 63;
    int wm = (wid >> 1) * 64, wn = (wid & 1) * 64;
    int l16 = lane & 15, q = lane >> 4;

    f32x4 acc[4][4];
    #pragma unroll
    for (int i = 0; i < 4; i++)
        #pragma unroll
        for (int j = 0; j < 4; j++)
            acc[i][j] = (f32x4){0.f, 0.f, 0.f, 0.f};

    const ushort* Abase = Ag + (size_t)bm * 128 * K;
    const ushort* Wbase = Wg + (size_t)bn * 128 * K;

    int r0 = tid >> 2, c0 = (tid & 3) << 3;
    const ushort* pA0 = Abase + (size_t)r0 * K + c0;
    const ushort* pA1 = Abase + (size_t)(r0 + 64) * K + c0;
    const ushort* pB0 = Wbase + (size_t)r0 * K + c0;
    const ushort* pB1 = Wbase + (size_t)(r0 + 64) * K + c0;

    uint4 pa0 = *(const uint4*)(pA0), pa1 = *(const uint4*)(pA1);
    uint4 pb0 = *(const uint4*)(pB0), pb1 = *(const uint4*)(pB1);

    for (int k0 = 0; k0 < K; k0 += 32) {
        *(uint4*)(sA + r0 * 40 + c0)        = pa0;
        *(uint4*)(sA + (r0 + 64) * 40 + c0) = pa1;
        *(uint4*)(sB + r0 * 40 + c0)        = pb0;
        *(uint4*)(sB + (r0 + 64) * 40 + c0) = pb1;
        __syncthreads();
        if (k0 + 32 < K) {
            pa0 = *(const uint4*)(pA0 + k0 + 32);
            pa1 = *(const uint4*)(pA1 + k0 + 32);
            pb0 = *(const uint4*)(pB0 + k0 + 32);
            pb1 = *(const uint4*)(pB1 + k0 + 32);
        }
        bf16x8 af[4], bfr[4];
        #pragma unroll
        for (int i = 0; i < 4; i++)
            af[i] = *(const bf16x8*)(sA + (wm + i * 16 + l16) * 40 + q * 8);
        #pragma unroll
        for (int j = 0; j < 4; j++)
            bfr[j] = *(const bf16x8*)(sB + (wn + j * 16 + l16) * 40 + q * 8);
        #pragma unroll
        for (int i = 0; i < 4; i++)
            #pragma unroll
            for (int j = 0; j < 4; j++)
                acc[i][j] = __builtin_amdgcn_mfma_f32_16x16x32_bf16(af[i], bfr[j], acc[i][j], 0, 0, 0);
        __syncthreads();
    }

    // bn 0..15 -> x half; 16..31 -> z half (each dense (NTOK, D_INNER) bf16)
    ushort* dst = (bn < 16) ? xq : zq;
    int row0 = bm * 128 + wm + q * 4;
    int col0 = (bn & 15) * 128 + wn + l16;
    #pragma unroll
    for (int i = 0; i < 4; i++)
        #pragma unroll
        for (int j = 0; j < 4; j++)
            #pragma unroll
            for (int r = 0; r < 4; r++)
                dst[(size_t)(row0 + i * 16 + r) * D_INNER + col0 + j * 16] =
                    f2b(acc[i][j][r]);
}

// ---------- K6: 64x64 MFMA GEMM, pipelined, f32 out ----------
__global__ __launch_bounds__(256) void gemm64_kernel(
    const ushort* __restrict__ Ag, const ushort* __restrict__ Wg,
    float* __restrict__ Cf, int M, int N, int K)
{
    __shared__ __align__(16) ushort sA[64 * 72];
    __shared__ __align__(16) ushort sB[64 * 72];
    int tid = threadIdx.x;
    int bm = blockIdx.x, bn = blockIdx.y;
    int wid = tid >> 6, lane = tid & 63;
    int wm = wid * 16;
    int l16 = lane & 15, q = lane >> 4;

    f32x4 acc[4];
    #pragma unroll
    for (int j = 0; j < 4; j++) acc[j] = (f32x4){0.f, 0.f, 0.f, 0.f};

    const ushort* Abase = Ag + (size_t)bm * 64 * K;
    const ushort* Wbase = Wg + (size_t)bn * 64 * K;

    int r0 = tid >> 3, c0 = (tid & 7) << 3;
    const ushort* pA0 = Abase + (size_t)r0 * K + c0;
    const ushort* pA1 = Abase + (size_t)(r0 + 32) * K + c0;
    const ushort* pB0 = Wbase + (size_t)r0 * K + c0;
    const ushort* pB1 = Wbase + (size_t)(r0 + 32) * K + c0;

    uint4 pa0 = *(const uint4*)(pA0), pa1 = *(const uint4*)(pA1);
    uint4 pb0 = *(const uint4*)(pB0), pb1 = *(const uint4*)(pB1);

    for (int k0 = 0; k0 < K; k0 += 64) {
        *(uint4*)(sA + r0 * 72 + c0)        = pa0;
        *(uint4*)(sA + (r0 + 32) * 72 + c0) = pa1;
        *(uint4*)(sB + r0 * 72 + c0)        = pb0;
        *(uint4*)(sB + (r0 + 32) * 72 + c0) = pb1;
        __syncthreads();
        if (k0 + 64 < K) {
            pa0 = *(const uint4*)(pA0 + k0 + 64);
            pa1 = *(const uint4*)(pA1 + k0 + 64);
            pb0 = *(const uint4*)(pB0 + k0 + 64);
            pb1 = *(const uint4*)(pB1 + k0 + 64);
        }
        #pragma unroll
        for (int ks = 0; ks < 2; ks++) {
            bf16x8 af = *(const bf16x8*)(sA + (wm + l16) * 72 + ks * 32 + q * 8);
            bf16x8 bfr[4];
            #pragma unroll
            for (int j = 0; j < 4; j++)
                bfr[j] = *(const bf16x8*)(sB + (j * 16 + l16) * 72 + ks * 32 + q * 8);
            #pragma unroll
            for (int j = 0; j < 4; j++)
                acc[j] = __builtin_amdgcn_mfma_f32_16x16x32_bf16(af, bfr[j], acc[j], 0, 0, 0);
        }
        __syncthreads();
    }

    int row0 = bm * 64 + wm + q * 4;
    int col0 = bn * 64 + l16;
    #pragma unroll
    for (int j = 0; j < 4; j++)
        #pragma unroll
        for (int r = 0; r < 4; r++)
            Cf[(size_t)(row0 + r) * N + col0 + j * 16] = acc[j][r];
}

// ---------- K3: causal depthwise conv (4 taps) + SiLU, bf16 in/out ----------
__global__ __launch_bounds__(256) void conv_silu_kernel(
    const ushort* __restrict__ xq, const float* __restrict__ cw,
    const float* __restrict__ cb, ushort* __restrict__ xcb)
{
    int idx = blockIdx.x * 256 + threadIdx.x;     // (token, d) flat over 4.19M
    int d = idx & (D_INNER - 1);
    int t = idx >> 11;
    int l = t & (LSEQ - 1), b = t >> 10;
    float4 w4 = *(const float4*)(cw + d * 4);
    float acc = cb[d];
    float wk[4] = {w4.x, w4.y, w4.z, w4.w};
    #pragma unroll
    for (int k = 0; k < 4; k++) {
        int ll = l - 3 + k;
        float xv = (ll >= 0) ? b2f(xq[(((size_t)(b * LSEQ + ll)) << 11) + d]) : 0.f;
        acc += xv * wk[k];
    }
    float sg = acc / (1.f + __expf(-acc));
    xcb[idx] = f2b(sg);
}

// ---------- K4a-1: xproj split-K partial GEMM ----------
__global__ __launch_bounds__(256) void xproj_partial_kernel(
    const ushort* __restrict__ xcb, const ushort* __restrict__ wq,
    float* __restrict__ partials)
{
    __shared__ __align__(16) ushort sA[128 * 32];
    __shared__ __align__(16) ushort sB[96 * 32];
    int tid = threadIdx.x;
    int bm = blockIdx.x, sl = blockIdx.y;
    int wid = tid >> 6, lane = tid & 63;
    int wm = wid * 32;
    int l16 = lane & 15, q = lane >> 4;

    f32x4 acc[2][6];
    #pragma unroll
    for (int i = 0; i < 2; i++)
        #pragma unroll
        for (int j = 0; j < 6; j++)
            acc[i][j] = (f32x4){0.f, 0.f, 0.f, 0.f};

    const ushort* Abase = xcb + (size_t)bm * 128 * D_INNER;
    int kbase = sl * (D_INNER / KSL);

    for (int kk = 0; kk < D_INNER / KSL; kk += 32) {
        int k0 = kbase + kk;
        __syncthreads();
        #pragma unroll
        for (int i = tid; i < 512; i += 256) {
            int r = i >> 2, c = (i & 3) << 3;
            *(uint4*)(sA + i * 8) = *(const uint4*)(Abase + (size_t)r * D_INNER + k0 + c);
        }
        for (int i = tid; i < 384; i += 256) {
            int r = i >> 2, c = (i & 3) << 3;
            *(uint4*)(sB + i * 8) = *(const uint4*)(wq + (size_t)r * D_INNER + k0 + c);
        }
        __syncthreads();
        bf16x8 af[2], bfr[6];
        #pragma unroll
        for (int i = 0; i < 2; i++)
            af[i] = *(const bf16x8*)(sA + (wm + i * 16 + l16) * 32 + q * 8);
        #pragma unroll
        for (int j = 0; j < 6; j++)
            bfr[j] = *(const bf16x8*)(sB + (j * 16 + l16) * 32 + q * 8);
        #pragma unroll
        for (int i = 0; i < 2; i++)
            #pragma unroll
            for (int j = 0; j < 6; j++)
                acc[i][j] = __builtin_amdgcn_mfma_f32_16x16x32_bf16(af[i], bfr[j], acc[i][j], 0, 0, 0);
    }

    float* out = partials + (size_t)sl * NTOK * 96;
    int row0 = bm * 128 + wm + q * 4;
    #pragma unroll
    for (int i = 0; i < 2; i++)
        #pragma unroll
        for (int j = 0; j < 6; j++)
            #pragma unroll
            for (int r = 0; r < 4; r++)
                out[(size_t)(row0 + i * 16 + r) * 96 + j * 16 + l16] = acc[i][j][r];
}

// ---------- K4a-2: xproj reduce (sum 16 partials) ----------
__global__ __launch_bounds__(256) void xproj_reduce_kernel(
    const float* __restrict__ partials, float* __restrict__ xdbl,
    ushort* __restrict__ xdbl64)
{
    int idx = blockIdx.x * 256 + threadIdx.x;    // 196608 outputs
    float s = 0.f;
    #pragma unroll
    for (int sl = 0; sl < KSL; sl++)
        s += partials[(size_t)sl * NTOK * 96 + idx];
    xdbl[idx] = s;
    int col = idx % 96;
    if (col < DT_RANK)
        xdbl64[(size_t)(idx / 96) * DT_RANK + col] = f2b(s);
}

// ---------- K4b: dt = softplus(xdbl64 @ dt_proj_w^T + b) -> bf16, coalesced ----------
__global__ __launch_bounds__(256) void dt_gemm_kernel(
    const ushort* __restrict__ xd64, const ushort* __restrict__ dtwq,
    const float* __restrict__ dtb, ushort* __restrict__ dtout)
{
    __shared__ __align__(16) ushort sA[64 * 72];
    __shared__ __align__(16) ushort sB[64 * 72];
    int tid = threadIdx.x;
    int bm = blockIdx.x, bn = blockIdx.y;
    int wid = tid >> 6, lane = tid & 63;
    int wm = wid * 16;
    int l16 = lane & 15, q = lane >> 4;

    const ushort* Abase = xd64 + (size_t)bm * 64 * DT_RANK;
    const ushort* Bbase = dtwq + (size_t)bn * 64 * DT_RANK;
    #pragma unroll
    for (int i = tid; i < 512; i += 256) {
        int r = i >> 3, c = (i & 7) << 3;
        *(uint4*)(sA + r * 72 + c) = *(const uint4*)(Abase + (size_t)r * DT_RANK + c);
        *(uint4*)(sB + r * 72 + c) = *(const uint4*)(Bbase + (size_t)r * DT_RANK + c);
    }
    __syncthreads();

    f32x4 acc[4];
    #pragma unroll
    for (int j = 0; j < 4; j++) acc[j] = (f32x4){0.f, 0.f, 0.f, 0.f};

    #pragma unroll
    for (int ks = 0; ks < 2; ks++) {
        bf16x8 af = *(const bf16x8*)(sA + (wm + l16) * 72 + ks * 32 + q * 8);
        bf16x8 bfr[4];
        #pragma unroll
        for (int j = 0; j < 4; j++)
            bfr[j] = *(const bf16x8*)(sB + (j * 16 + l16) * 72 + ks * 32 + q * 8);
        #pragma unroll
        for (int j = 0; j < 4; j++)
            acc[j] = __builtin_amdgcn_mfma_f32_16x16x32_bf16(af, bfr[j], acc[j], 0, 0, 0);
    }

    __syncthreads();
    #pragma unroll
    for (int j = 0; j < 4; j++) {
        float bias = dtb[bn * 64 + j * 16 + l16];
        #pragma unroll
        for (int r = 0; r < 4; r++) {
            float s = acc[j][r] + bias;
            float sp = (s > 20.f) ? s : log1pf(__expf(s));
            sA[(wm + q * 4 + r) * 72 + j * 16 + l16] = f2b(sp);
        }
    }
    __syncthreads();
    int row0 = bm * 64, col0 = bn * 64;
    #pragma unroll
    for (int rep = 0; rep < 2; rep++) {
        int off = rep * 2048 + tid * 8;
        int row = off >> 6, col = off & 63;
        *(uint4*)(dtout + (size_t)(row0 + row) * D_INNER + col0 + col) =
            *(const uint4*)(sA + row * 72 + col);
    }
}

// ---------- K5a: scan pass A — lane-owns-d, 16 n-states in registers ----------
__global__ __launch_bounds__(256) void scan_partA_kernel(
    const ushort* __restrict__ dt, const ushort* __restrict__ xcq,
    const float* __restrict__ xdbl, const float* __restrict__ Alog,
    float2* __restrict__ ch1, float2* __restrict__ ch2)
{
    __shared__ float sBC[LC][32];
    int bid = blockIdx.x;
    int g = bid & 7;
    int c = (bid >> 3) & (NCH - 1);
    int b = bid >> 8;
    int tid = threadIdx.x;
    int lane = tid & 63, wid = tid >> 6;
    int d = g * 256 + wid * 64 + lane;
    int l0 = c * LC;

    {   // stage B/C tile
        int r = tid >> 3, c4 = (tid & 7) * 4;
        *(float4*)&sBC[r][c4] =
            *(const float4*)(xdbl + ((size_t)(b * LSEQ + l0 + r)) * 96 + 64 + c4);
    }
    float A[16];
    #pragma unroll
    for (int k = 0; k < 4; k++)
        *(float4*)&A[k * 4] = *(const float4*)(Alog + d * D_STATE + k * 4);
    #pragma unroll
    for (int n = 0; n < 16; n++) A[n] = -__expf(A[n]);
    __syncthreads();

    const ushort* dtp = dt  + ((size_t)(b * LSEQ + l0)) * D_INNER + d;
    const ushort* xcp = xcq + ((size_t)(b * LSEQ + l0)) * D_INNER + d;

    float h[16], ap[16];
    #pragma unroll
    for (int n = 0; n < 16; n++) { h[n] = 0.f; ap[n] = 1.f; }

    for (int l = 0; l < LC; l++) {
        float dtv = b2f(dtp[(size_t)l * D_INNER]);
        float xcv = b2f(xcp[(size_t)l * D_INNER]);
        float t = dtv * xcv;
        float Bv[16];
        #pragma unroll
        for (int k = 0; k < 4; k++)
            *(float4*)&Bv[k * 4] = *(const float4*)&sBC[l][k * 4];
        #pragma unroll
        for (int n = 0; n < 16; n++) {
            float a = __expf(dtv * A[n]);
            h[n] = h[n] * a + t * Bv[n];
            ap[n] *= a;
        }
    }

    float2* outp = (c < 16 ? ch1 : ch2) +
                   ((size_t)((b * 16 + (c & 15)) * D_INNER + d)) * D_STATE;
    #pragma unroll
    for (int n = 0; n < 16; n += 2) {
        float4 v = {ap[n], h[n], ap[n + 1], h[n + 1]};
        *(float4*)&outp[n] = v;
    }
}

// ---------- K5b: stitch (in-place: .x becomes h_init for that chunk) ----------
__global__ __launch_bounds__(256) void scan_partB_kernel(
    float2* __restrict__ ch1, float2* __restrict__ ch2)
{
    int kk = blockIdx.x * 256 + threadIdx.x;   // 65536 = b(2) x d(2048) x n(16)
    int b = kk >> 15, dn = kk & 32767;
    float run = 0.f;
    #pragma unroll
    for (int c = 0; c < NCH; c++) {
        float2* p = (c < 16 ? ch1 : ch2) +
                    (size_t)(b * 16 + (c & 15)) * 32768 + dn;
        float2 v = *p;
        p->x = run;                 // h_init entering chunk c
        run = v.x * run + v.y;
    }
}

// ---------- K5c: scan pass C — lane-owns-d, fused C-proj + D-skip + gate ----------
__global__ __launch_bounds__(256) void scan_partC_kernel(
    const ushort* __restrict__ dt, const ushort* __restrict__ xcq,
    const float* __restrict__ xdbl, const ushort* __restrict__ zq,
    const float* __restrict__ Alog, const float* __restrict__ Dp,
    const float2* __restrict__ ch1, const float2* __restrict__ ch2,
    ushort* __restrict__ yg)
{
    __shared__ float sBC[LC][32];
    int bid = blockIdx.x;
    int g = bid & 7;
    int c = (bid >> 3) & (NCH - 1);
    int b = bid >> 8;
    int tid = threadIdx.x;
    int lane = tid & 63, wid = tid >> 6;
    int d = g * 256 + wid * 64 + lane;
    int l0 = c * LC;

    {
        int r = tid >> 3, c4 = (tid & 7) * 4;
        *(float4*)&sBC[r][c4] =
            *(const float4*)(xdbl + ((size_t)(b * LSEQ + l0 + r)) * 96 + 64 + c4);
    }
    float A[16];
    #pragma unroll
    for (int k = 0; k < 4; k++)
        *(float4*)&A[k * 4] = *(const float4*)(Alog + d * D_STATE + k * 4);
    #pragma unroll
    for (int n = 0; n < 16; n++) A[n] = -__expf(A[n]);
    float Dd = Dp[d];

    const float2* hip_ = (c < 16 ? ch1 : ch2) +
                         ((size_t)((b * 16 + (c & 15)) * D_INNER + d)) * D_STATE;
    float h[16];
    #pragma unroll
    for (int n = 0; n < 16; n += 2) {
        float4 v = *(const float4*)&hip_[n];
        h[n] = v.x; h[n + 1] = v.z;
    }
    __syncthreads();

    const ushort* dtp = dt  + ((size_t)(b * LSEQ + l0)) * D_INNER + d;
    const ushort* xcp = xcq + ((size_t)(b * LSEQ + l0)) * D_INNER + d;
    const ushort* zp  = zq  + ((size_t)(b * LSEQ + l0)) * D_INNER + d;
    ushort* yp = yg + ((size_t)(b * LSEQ + l0)) * D_INNER + d;

    for (int l = 0; l < LC; l++) {
        float dtv = b2f(dtp[(size_t)l * D_INNER]);
        float xcv = b2f(xcp[(size_t)l * D_INNER]);
        float zv  = b2f(zp[(size_t)l * D_INNER]);
        float t = dtv * xcv;
        float Bv[16], Cv[16];
        #pragma unroll
        for (int k = 0; k < 4; k++) {
            *(float4*)&Bv[k * 4] = *(const float4*)&sBC[l][k * 4];
            *(float4*)&Cv[k * 4] = *(const float4*)&sBC[l][16 + k * 4];
        }
        float p0 = 0.f, p1 = 0.f, p2 = 0.f, p3 = 0.f;
        #pragma unroll
        for (int n = 0; n < 16; n += 4) {
            float a0 = __expf(dtv * A[n]);
            float a1 = __expf(dtv * A[n + 1]);
            float a2 = __expf(dtv * A[n + 2]);
            float a3 = __expf(dtv * A[n + 3]);
            h[n]     = h[n] * a0 + t * Bv[n];
            h[n + 1] = h[n + 1] * a1 + t * Bv[n + 1];
            h[n + 2] = h[n + 2] * a2 + t * Bv[n + 2];
            h[n + 3] = h[n + 3] * a3 + t * Bv[n + 3];
            p0 += h[n] * Cv[n];
            p1 += h[n + 1] * Cv[n + 1];
            p2 += h[n + 2] * Cv[n + 2];
            p3 += h[n + 3] * Cv[n + 3];
        }
        float p = (p0 + p1) + (p2 + p3);
        float y = p + Dd * xcv;
        float sz = zv / (1.f + __expf(-zv));
        yp[(size_t)l * D_INNER] = f2b(y * sz);
    }
}

extern "C" void kernel_launch(void* const* d_in, const int* in_sizes, int n_in,
                              void* d_out, int out_size, void* d_ws, size_t ws_size,
                              hipStream_t stream)
{
    const float* hs      = (const float*)d_in[0];
    const float* norm_w  = (const float*)d_in[1];
    const float* inproj  = (const float*)d_in[2];
    const float* convw   = (const float*)d_in[3];
    const float* convb   = (const float*)d_in[4];
    const float* xprojw  = (const float*)d_in[5];
    const float* dtw     = (const float*)d_in[6];
    const float* dtb     = (const float*)d_in[7];
    const float* alog    = (const float*)d_in[8];
    const float* dvec    = (const float*)d_in[9];
    const float* outproj = (const float*)d_in[10];

    float* out_main  = (float*)d_out;                        // (B,L,D_MODEL) f32
    float* out_resid = (float*)d_out + (size_t)NTOK * D_MODEL;

    // all buffers disjoint (no overlays); total ≈ 92.3MB
    char* ws = (char*)d_ws;
    ushort* xq      = (ushort*)(ws);                         // 8.4MB x-half bf16
    ushort* zq      = (ushort*)(ws +  9437184);              // 8.4MB z-half bf16
    ushort* xcb     = (ushort*)(ws + 18874368);              // 8.4MB conv out bf16
    ushort* dtq     = (ushort*)(ws + 28311552);              // 8.4MB dt bf16
    float2* ch1     = (float2*)(ws + 37748736);              // 8.4MB chunks 0..15
    float2* ch2     = (float2*)(ws + 47185920);              // 8.4MB chunks 16..31
    float*  xdbl    = (float*) (ws + 56623104);              // 768KB
    ushort* xd64    = (ushort*)(ws + 57671680);              // 256KB
    ushort* xpw_b   = (ushort*)(ws + 58195968);              // 384KB
    ushort* dtw_b   = (ushort*)(ws + 58720256);              // 256KB
    ushort* wIn     = (ushort*)(ws + 59768832);              // 8.4MB
    ushort* wOut    = (ushort*)(ws + 69206016);              // 4.2MB
    ushort* h_bf16  = (ushort*)(ws + 74448896);              // 4.2MB
    ushort* yg_bf16 = (ushort*)(ws + 18874368);              // reuse xcb? NO — see below
    float*  xprojP  = (float*) (ws + 79691776);              // 12.6MB partials

    // yg must not alias xcb (xcb is read by partC). Place yg in xprojP region:
    // xprojP is dead after xproj_reduce; yg written by partC, read by K6. Disjoint lifetime.
    yg_bf16 = (ushort*)(ws + 79691776);

    // K0: all weight conversions (1,654,784 quads)
    cvt_all_kernel<<<6464, 256, 0, stream>>>(
        inproj, outproj, xprojw, dtw, wIn, wOut, xpw_b, dtw_b);

    // K1: RMSNorm + residual copy
    rmsnorm_kernel<<<NTOK, 256, 0, stream>>>(hs, norm_w, h_bf16, out_resid);

    // K2: xz GEMM -> bf16 x/z halves
    gemm_xz_kernel<<<dim3(NTOK / 128, (2 * D_INNER) / 128), 256, 0, stream>>>(
        h_bf16, wIn, xq, zq, D_MODEL);

    // K3: conv + SiLU (bf16 in/out)
    conv_silu_kernel<<<(NTOK * D_INNER) / 256, 256, 0, stream>>>(
        xq, convw, convb, xcb);

    // K4a: x_dbl GEMM — split-K partials then reduce
    xproj_partial_kernel<<<dim3(NTOK / 128, KSL), 256, 0, stream>>>(
        xcb, xpw_b, xprojP);
    xproj_reduce_kernel<<<NTOK * 96 / 256, 256, 0, stream>>>(xprojP, xdbl, xd64);

    // K4b: dt GEMM + bias + softplus -> bf16
    dt_gemm_kernel<<<dim3(NTOK / 64, D_INNER / 64), 256, 0, stream>>>(
        xd64, dtw_b, dtb, dtq);

    // K5: chunked parallel scan, lane-owns-d
    scan_partA_kernel<<<512, 256, 0, stream>>>(dtq, xcb, xdbl, alog, ch1, ch2);
    scan_partB_kernel<<<256, 256, 0, stream>>>(ch1, ch2);
    scan_partC_kernel<<<512, 256, 0, stream>>>(dtq, xcb, xdbl, zq,
                                               alog, dvec, ch1, ch2, yg_bf16);

    // K6: out = yg @ out_proj_w^T -> f32
    gemm64_kernel<<<dim3(NTOK / 64, D_MODEL / 64), 256, 0, stream>>>(
        yg_bf16, wOut, out_main, NTOK, D_MODEL, D_INNER);
}